// Round 12
// baseline (858.035 us; speedup 1.0000x reference)
//
#include <hip/hip_runtime.h>
#include <cstdint>
#include <cstddef>
#include <cmath>

#define TN   8192
#define DD   512
#define NPER 4
#define KNN  5

typedef _Float16 f16x8 __attribute__((ext_vector_type(8)));
typedef _Float16 f16x4 __attribute__((ext_vector_type(4)));
typedef float    f32x4 __attribute__((ext_vector_type(4)));
typedef unsigned long long u64;

// key = sq_row - 2 * accHH / 4096^2  ->  fmaf(acc, -2^-23, sq_row)
#define KSCALE (-1.1920928955078125e-07f)

// ---------------------------------------------------------------------------
// Monotone pack: (f32 key, idx) -> u64; u64-ascending == (key, idx) ascending.
// ---------------------------------------------------------------------------
__device__ __forceinline__ u64 packkey(float key, int idx) {
  unsigned int kb = __float_as_uint(key);
  kb ^= (((int)kb >> 31) | 0x80000000u);
  return ((u64)kb << 32) | (unsigned int)idx;
}

__device__ __forceinline__ void ins8(u64 v, u64 tv[8]) {
  if (v < tv[7]) {
    tv[7] = v;
#pragma unroll
    for (int s = 7; s > 0; --s) {
      u64 lo = tv[s] < tv[s-1] ? tv[s] : tv[s-1];
      u64 hi = tv[s] < tv[s-1] ? tv[s-1] : tv[s];
      tv[s-1] = lo; tv[s] = hi;
    }
  }
}

// cap-5 sorted insert (risk ~2e-5; see R10/R11 analysis).
__device__ __forceinline__ void ins5u(u64 v, u64 tv[5]) {
  if (v < tv[4]) {
    tv[4] = v;
#pragma unroll
    for (int s = 4; s > 0; --s) {
      u64 lo = tv[s] < tv[s-1] ? tv[s] : tv[s-1];
      u64 hi = tv[s] < tv[s-1] ? tv[s-1] : tv[s];
      tv[s-1] = lo; tv[s] = hi;
    }
  }
}

// ---------------------------------------------------------------------------
// Kernel 0: hi fp16 of X*4096 AND exact rowsq. One wave per row.
// ---------------------------------------------------------------------------
__global__ void prep_sq(const float* __restrict__ X,
                        _Float16* __restrict__ H, float* __restrict__ rowsq) {
  const int row  = (int)blockIdx.x * 4 + ((int)threadIdx.x >> 6);
  const int lane = (int)threadIdx.x & 63;
  const float4* xr = (const float4*)(X + (size_t)row * DD);
  const float4 a = xr[lane];
  const float4 b = xr[lane + 64];
  float xa[4] = {a.x, a.y, a.z, a.w};
  float xb[4] = {b.x, b.y, b.z, b.w};
  f16x4 ha, hb;
#pragma unroll
  for (int j = 0; j < 4; ++j) {
    ha[j] = (_Float16)(xa[j] * 4096.f);
    hb[j] = (_Float16)(xb[j] * 4096.f);
  }
  f16x4* Hr = (f16x4*)(H + (size_t)row * DD);
  Hr[lane] = ha; Hr[lane + 64] = hb;

  float s = a.x*a.x + a.y*a.y + a.z*a.z + a.w*a.w
          + b.x*b.x + b.y*b.y + b.z*b.z + b.w*b.w;
#pragma unroll
  for (int off = 32; off >= 1; off >>= 1) s += __shfl_down(s, off, 64);
  if (lane == 0) rowsq[row] = s;
}

// ---------------------------------------------------------------------------
// Kernel 1: HH screening GEMM over the TRIANGULAR tile set (rb <= cb; 2080
// tiles instead of 4096 — d2 is symmetric). Per tile, two MFMA passes:
//   acc [rt][cf] = mfma(af[rt], bf[cf])  -> tile            (rows x cols)
//   acc2[rt][cf] = mfma(bf[rt], af[cf])  -> transposed tile (cols x rows)
// Same total MFMA as before, but LOADS/TILES/TRANSACTIONS HALVE — and R11's
// diagnosis is that the wall is per-CU memory transaction rate (MfmaUtil 7.3%
// at ~2800 idle cyc per 77-cyc MFMA block; both staged R8 and direct R11 hit
// the same floor proportional to bytes loaded).
// Col-mode epilogue (proven R11) runs on acc -> partials slot rb for centers
// = cols. Transposed epilogue = same code under role swap (centers = rows,
// candidates = cols, LDS merge across wc pairs) -> slot cb, skipped on the
// diagonal. Slot audit: center in block J gets rb=0..J (col-mode) +
// cb=J+1..63 (transpose) = exactly 64 slots, no collision.
// C layout (m89): col = lane&15, row = 4*(lane>>4) + reg.
// ---------------------------------------------------------------------------
__launch_bounds__(256, 2)   // acc+acc2 = 128 + frags 64 + addr/epilogue -> ~210
__global__ void gemm_top8(const _Float16* __restrict__ Hp,
                          const float* __restrict__ rowsq, u64* __restrict__ partials) {
  __shared__ u64 mg[128 * 8];                 // 8 KB merge buffer
  const int tid  = (int)threadIdx.x;
  const int lane = tid & 63;
  const int w    = tid >> 6;                  // wave 0..3
  const int wr   = w >> 1, wc = w & 1;        // 2x2 wave grid
  // XCD swizzle (2080 % 8 == 0 -> bijective), then triangular decode:
  // q = cb*(cb+1)/2 + rb, rb <= cb  (rb fastest -> consecutive q share B panel)
  const int q    = ((int)blockIdx.x & 7) * 260 + ((int)blockIdx.x >> 3);
  int cb = (int)((sqrtf(8.0f * (float)q + 1.0f) - 1.0f) * 0.5f);
  while ((cb + 1) * (cb + 2) / 2 <= q) ++cb;  // float-rounding fixup
  while (cb * (cb + 1) / 2 > q) --cb;
  const int rb   = q - cb * (cb + 1) / 2;
  const int row0 = rb * 128;
  const int jb   = cb * 128;
  const int lgrp = lane >> 4;                 // k-group / C row-group
  const int lidx = lane & 15;                 // A-row / B-col within frag

  // per-lane fragment base pointers (byte arithmetic; 16B aligned)
  const char* Apb = (const char*)(Hp + (size_t)(row0 + wr*64 + lidx) * DD) + lgrp*16;
  const char* Bpb = (const char*)(Hp + (size_t)(jb   + wc*64 + lidx) * DD) + lgrp*16;

#define LOADF(aa, bb, ksv) do {                                                 \
    _Pragma("unroll")                                                           \
    for (int t = 0; t < 4; ++t)                                                 \
      aa[t] = *(const f16x8*)(Apb + t*16384 + (ksv)*64);                        \
    _Pragma("unroll")                                                           \
    for (int u = 0; u < 4; ++u)                                                 \
      bb[u] = *(const f16x8*)(Bpb + u*16384 + (ksv)*64);                        \
  } while (0)

#define MFMAS(dst, aa, bb) do {                                                 \
    _Pragma("unroll")                                                           \
    for (int rt = 0; rt < 4; ++rt)                                              \
      _Pragma("unroll")                                                         \
      for (int cf = 0; cf < 4; ++cf)                                            \
        dst[rt][cf] = __builtin_amdgcn_mfma_f32_16x16x32_f16(aa[rt], bb[cf],    \
                                                             dst[rt][cf], 0, 0, 0); \
  } while (0)

  f32x4 acc[4][4] = {};    // (row r, col c)
  f32x4 acc2[4][4] = {};   // transposed: ("row" = col c, "col" = row r)
  f16x8 a0[4], b0[4], a1[4], b1[4];

  LOADF(a0, b0, 0);
  LOADF(a1, b1, 1);
#pragma unroll
  for (int ks = 0; ks < 16; ks += 2) {        // K = 512 in chunks of 32
    MFMAS(acc,  a0, b0);
    MFMAS(acc2, b0, a0);
    if (ks + 2 < 16) LOADF(a0, b0, ks + 2);
    MFMAS(acc,  a1, b1);
    MFMAS(acc2, b1, a1);
    if (ks + 3 < 16) LOADF(a1, b1, ks + 3);
  }

  // ==== epilogue pass 1: col-mode on acc (verbatim R11, proven) ====
  {
    float4 sqr[4];
#pragma unroll
    for (int t = 0; t < 4; ++t)
      sqr[t] = *(const float4*)(rowsq + row0 + wr*64 + t*16 + lgrp*4);

#pragma unroll
    for (int cf = 0; cf < 4; ++cf) {
      const int jc = jb + wc*64 + cf*16 + lidx;   // center column
      u64 t5[5];
#pragma unroll
      for (int s = 0; s < 5; ++s) t5[s] = ~0ull;
#pragma unroll
      for (int t = 0; t < 4; ++t) {
        const int rbase = row0 + wr*64 + t*16 + lgrp*4;
        float key;
        key = fmaf(acc[t][cf][0], KSCALE, sqr[t].x); if (rbase+0 != jc) ins5u(packkey(key, rbase+0), t5);
        key = fmaf(acc[t][cf][1], KSCALE, sqr[t].y); if (rbase+1 != jc) ins5u(packkey(key, rbase+1), t5);
        key = fmaf(acc[t][cf][2], KSCALE, sqr[t].z); if (rbase+2 != jc) ins5u(packkey(key, rbase+2), t5);
        key = fmaf(acc[t][cf][3], KSCALE, sqr[t].w); if (rbase+3 != jc) ins5u(packkey(key, rbase+3), t5);
      }
      // SNAPSHOT butterfly merges (R10 lesson)
      u64 t8[8];
#pragma unroll
      for (int s = 0; s < 5; ++s) t8[s] = t5[s];
#pragma unroll
      for (int s = 5; s < 8; ++s) t8[s] = ~0ull;
      {
        u64 ov[5];
#pragma unroll
        for (int s = 0; s < 5; ++s) ov[s] = __shfl_xor(t5[s], 16, 64);   // d=16
#pragma unroll
        for (int s = 0; s < 5; ++s) ins8(ov[s], t8);
      }
      {
        u64 ov[8];
#pragma unroll
        for (int s = 0; s < 8; ++s) ov[s] = __shfl_xor(t8[s], 32, 64);   // d=32
#pragma unroll
        for (int s = 0; s < 8; ++s) ins8(ov[s], t8);
      }
      // wr-pair merge via LDS (two wr waves = two 64-row halves)
      if (wr == 1 && lane < 16) {
#pragma unroll
        for (int s = 0; s < 8; ++s) mg[(wc*64 + cf*16 + lidx)*8 + s] = t8[s];
      }
      __syncthreads();
      if (wr == 0 && lane < 16) {
        const u64* om = &mg[(wc*64 + cf*16 + lidx)*8];
#pragma unroll
        for (int s = 0; s < 8; ++s) ins8(om[s], t8);
        u64* pw = partials + ((size_t)jc * 64 + rb) * 8;
#pragma unroll
        for (int s = 0; s < 8; ++s) pw[s] = t8[s];
      }
      __syncthreads();
    }
  }

  // ==== epilogue pass 2: transposed tile (skip on diagonal) ====
  // acc2[t][cf][q]: candidate = jb + wc*64 + t*16 + lgrp*4 + q (a col),
  //                 center    = row0 + wr*64 + cf*16 + lidx     (a row).
  // Same machinery; LDS merge across wc pairs; write slot cb.
  if (rb != cb) {
    float4 sqr2[4];
#pragma unroll
    for (int t = 0; t < 4; ++t)
      sqr2[t] = *(const float4*)(rowsq + jb + wc*64 + t*16 + lgrp*4);

#pragma unroll
    for (int cf = 0; cf < 4; ++cf) {
      const int jc2 = row0 + wr*64 + cf*16 + lidx;  // center row
      u64 t5[5];
#pragma unroll
      for (int s = 0; s < 5; ++s) t5[s] = ~0ull;
#pragma unroll
      for (int t = 0; t < 4; ++t) {
        const int rbase = jb + wc*64 + t*16 + lgrp*4;   // candidate cols
        float key;
        key = fmaf(acc2[t][cf][0], KSCALE, sqr2[t].x); ins5u(packkey(key, rbase+0), t5);
        key = fmaf(acc2[t][cf][1], KSCALE, sqr2[t].y); ins5u(packkey(key, rbase+1), t5);
        key = fmaf(acc2[t][cf][2], KSCALE, sqr2[t].z); ins5u(packkey(key, rbase+2), t5);
        key = fmaf(acc2[t][cf][3], KSCALE, sqr2[t].w); ins5u(packkey(key, rbase+3), t5);
      }
      u64 t8[8];
#pragma unroll
      for (int s = 0; s < 5; ++s) t8[s] = t5[s];
#pragma unroll
      for (int s = 5; s < 8; ++s) t8[s] = ~0ull;
      {
        u64 ov[5];
#pragma unroll
        for (int s = 0; s < 5; ++s) ov[s] = __shfl_xor(t5[s], 16, 64);   // d=16
#pragma unroll
        for (int s = 0; s < 5; ++s) ins8(ov[s], t8);
      }
      {
        u64 ov[8];
#pragma unroll
        for (int s = 0; s < 8; ++s) ov[s] = __shfl_xor(t8[s], 32, 64);   // d=32
#pragma unroll
        for (int s = 0; s < 8; ++s) ins8(ov[s], t8);
      }
      // wc-pair merge via LDS (two wc waves = two 64-col candidate halves)
      if (wc == 1 && lane < 16) {
#pragma unroll
        for (int s = 0; s < 8; ++s) mg[(wr*64 + cf*16 + lidx)*8 + s] = t8[s];
      }
      __syncthreads();
      if (wc == 0 && lane < 16) {
        const u64* om = &mg[(wr*64 + cf*16 + lidx)*8];
#pragma unroll
        for (int s = 0; s < 8; ++s) ins8(om[s], t8);
        u64* pw = partials + ((size_t)jc2 * 64 + cb) * 8;
#pragma unroll
        for (int s = 0; s < 8; ++s) pw[s] = t8[s];
      }
      __syncthreads();
    }
  }
#undef LOADF
#undef MFMAS
}

// ---------------------------------------------------------------------------
// Kernel 2: fold 64 partial top-8 lists per center -> cand[T][8] (sorted u64).
// (verbatim R8/R11, proven)
// ---------------------------------------------------------------------------
__global__ void merge_nn8(const u64* __restrict__ parts, u64* __restrict__ cand) {
  const int j    = (int)blockIdx.x * 4 + ((int)threadIdx.x >> 6);
  const int lane = (int)threadIdx.x & 63;
  u64 tv[8];
  const u64* p0 = parts + ((size_t)j * 64 + lane) * 8;
#pragma unroll
  for (int s = 0; s < 8; ++s) tv[s] = p0[s];
#pragma unroll
  for (int d = 1; d < 64; d <<= 1) {
    u64 ov[8];
#pragma unroll
    for (int s = 0; s < 8; ++s) ov[s] = __shfl_xor(tv[s], d, 64);
#pragma unroll
    for (int s = 0; s < 8; ++s) ins8(ov[s], tv);
  }
  if (lane == 0) {
#pragma unroll
    for (int s = 0; s < 8; ++s) cand[(size_t)j*8 + s] = tv[s];
  }
}

// ---------------------------------------------------------------------------
// Kernel 3: exact fp32 refine of the 8 candidates per center -> nn[T][5].
// (verbatim R8/R11, proven)
// ---------------------------------------------------------------------------
__global__ void refine_nn(const float* __restrict__ X, const float* __restrict__ rowsq,
                          const u64* __restrict__ cand, int* __restrict__ nn) {
  const int j    = (int)blockIdx.x * 4 + ((int)threadIdx.x >> 6);   // center
  const int lane = (int)threadIdx.x & 63;
  const float4* xj = (const float4*)(X + (size_t)j * DD);
  const float4 qa = xj[lane];
  const float4 qb = xj[lane + 64];
  u64 best[8];
#pragma unroll
  for (int s = 0; s < 8; ++s) best[s] = ~0ull;
#pragma unroll
  for (int c = 0; c < 8; ++c) {
    const int r = (int)(unsigned int)cand[(size_t)j*8 + c];
    const float4* xr_ = (const float4*)(X + (size_t)r * DD);
    const float4 a = xr_[lane];
    const float4 b = xr_[lane + 64];
    float d = a.x*qa.x + a.y*qa.y + a.z*qa.z + a.w*qa.w
            + b.x*qb.x + b.y*qb.y + b.z*qb.z + b.w*qb.w;
#pragma unroll
    for (int off = 32; off >= 1; off >>= 1) d += __shfl_xor(d, off, 64);
    const float key = fmaf(-2.f, d, rowsq[r]);
    ins8(packkey(key, r), best);              // every lane: identical result
  }
  if (lane == 0) {
#pragma unroll
    for (int s = 0; s < KNN; ++s) nn[j*KNN + s] = (int)(unsigned int)best[s];
  }
}

// ---------------------------------------------------------------------------
// Kernel 4: synthesis  out[i*4+p] = x_i + g * (x_nn - x_i)  (verbatim, proven)
// ---------------------------------------------------------------------------
__global__ void synth_kernel(const float* __restrict__ X, const int* __restrict__ nn,
                             const float* __restrict__ gaps, const int* __restrict__ choice,
                             float* __restrict__ out) {
  const float4* X4 = (const float4*)X;
  float4* O4 = (float4*)out;
  const int base = (int)blockIdx.x * 256 + (int)threadIdx.x;
#pragma unroll
  for (int it = 0; it < 8; ++it) {
    const int f    = base + it * (2048 * 256);
    const int orow = f >> 7;
    const int d4   = f & 127;
    const int i    = orow >> 2;
    const int ch   = choice[orow];
    const int nr   = nn[i * KNN + ch];
    const float g  = gaps[orow];
    const float4 xi = X4[(size_t)i  * 128 + d4];
    const float4 xn = X4[(size_t)nr * 128 + d4];
    float4 r;
    r.x = fmaf(g, xn.x - xi.x, xi.x);
    r.y = fmaf(g, xn.y - xi.y, xi.y);
    r.z = fmaf(g, xn.z - xi.z, xi.z);
    r.w = fmaf(g, xn.w - xi.w, xi.w);
    O4[(size_t)orow * 128 + d4] = r;
  }
}

// ---------------------------------------------------------------------------
// d_out (64 MB) scratch layout: H[8MB) | partials u64[8M..40M) | cand[40M..40.5M)
// — synth fully rewrites d_out last. d_ws: rowsq[32KB) + nn[160KB).
// ---------------------------------------------------------------------------
extern "C" void kernel_launch(void* const* d_in, const int* in_sizes, int n_in,
                              void* d_out, int out_size, void* d_ws, size_t ws_size,
                              hipStream_t stream) {
  const float* X      = (const float*)d_in[0];
  const float* gaps   = (const float*)d_in[1];
  const int*   choice = (const int*)  d_in[2];
  float* out = (float*)d_out;

  _Float16* Hbuf  = (_Float16*)d_out;                       // [0, 8M)
  u64*      parts = (u64*)((char*)d_out + 8388608);         // [8M, 40M)
  u64*      cand  = (u64*)((char*)d_out + 41943040);        // [40M, 40.5M)

  float* rowsq = (float*)d_ws;                              // 32 KB
  int*   nn    = (int*)((char*)d_ws + TN * 4);              // 160 KB

  prep_sq     <<<2048, 256, 0, stream>>>(X, Hbuf, rowsq);
  gemm_top8   <<<2080, 256, 0, stream>>>(Hbuf, rowsq, parts);
  merge_nn8   <<<2048, 256, 0, stream>>>(parts, cand);
  refine_nn   <<<2048, 256, 0, stream>>>(X, rowsq, cand, nn);
  synth_kernel<<<2048, 256, 0, stream>>>(X, nn, gaps, choice, out);
}

// Round 13
// 376.737 us; speedup vs baseline: 2.2775x; 2.2775x over previous
//
#include <hip/hip_runtime.h>
#include <cstdint>
#include <cstddef>

#define TN   8192
#define DD   512
#define NPER 4
#define KNN  5

typedef _Float16 f16x8 __attribute__((ext_vector_type(8)));
typedef _Float16 f16x4 __attribute__((ext_vector_type(4)));
typedef float    f32x4 __attribute__((ext_vector_type(4)));
typedef unsigned int  u32;
typedef unsigned long long u64;

// key = sq_row - 2 * accHH / 4096^2  ->  fmaf(acc, -2^-23, sq_row)
#define KSCALE (-1.1920928955078125e-07f)

// ---------------------------------------------------------------------------
// u32 screen key: monotone f32 map, top 19 bits | 13-bit row idx.
// Quantization step ~2^-10 relative (~1.0 abs at key~1000) << NN rank gaps
// (~3); exact order restored by fp32 refine; 8-slot screen vs 5 needed gives
// slack. u32 compares/min/max are single VALU ops (u64 chain was the R11 wall).
// ---------------------------------------------------------------------------
__device__ __forceinline__ u32 pk32(float key, int idx) {
  u32 kb = __float_as_uint(key);
  kb ^= (((int)kb >> 31) | 0x80000000u);
  return (kb & 0xFFFFE000u) | (u32)idx;
}

// branchless sorted-insert sweeps (v_min_u32/v_max_u32 pairs, no branches —
// R11 lesson: guarded chains run at wave granularity, P(any lane fires)~1).
__device__ __forceinline__ void swins5(u32 v, u32 t[5]) {
#pragma unroll
  for (int s = 0; s < 5; ++s) {
    u32 lo = v < t[s] ? v : t[s];
    u32 hi = v < t[s] ? t[s] : v;
    t[s] = lo; v = hi;
  }
}
__device__ __forceinline__ void swins8(u32 v, u32 t[8]) {
#pragma unroll
  for (int s = 0; s < 8; ++s) {
    u32 lo = v < t[s] ? v : t[s];
    u32 hi = v < t[s] ? t[s] : v;
    t[s] = lo; v = hi;
  }
}

// u64 exact insert for the tiny refine kernel (proven R8-R12)
__device__ __forceinline__ u64 packkey64(float key, int idx) {
  u32 kb = __float_as_uint(key);
  kb ^= (((int)kb >> 31) | 0x80000000u);
  return ((u64)kb << 32) | (u32)idx;
}
__device__ __forceinline__ void ins8_64(u64 v, u64 tv[8]) {
  if (v < tv[7]) {
    tv[7] = v;
#pragma unroll
    for (int s = 7; s > 0; --s) {
      u64 lo = tv[s] < tv[s-1] ? tv[s] : tv[s-1];
      u64 hi = tv[s] < tv[s-1] ? tv[s-1] : tv[s];
      tv[s-1] = lo; tv[s] = hi;
    }
  }
}

// ---------------------------------------------------------------------------
// Kernel 0: hi fp16 of X*4096 AND exact rowsq. One wave per row.
// ---------------------------------------------------------------------------
__global__ void prep_sq(const float* __restrict__ X,
                        _Float16* __restrict__ H, float* __restrict__ rowsq) {
  const int row  = (int)blockIdx.x * 4 + ((int)threadIdx.x >> 6);
  const int lane = (int)threadIdx.x & 63;
  const float4* xr = (const float4*)(X + (size_t)row * DD);
  const float4 a = xr[lane];
  const float4 b = xr[lane + 64];
  float xa[4] = {a.x, a.y, a.z, a.w};
  float xb[4] = {b.x, b.y, b.z, b.w};
  f16x4 ha, hb;
#pragma unroll
  for (int j = 0; j < 4; ++j) {
    ha[j] = (_Float16)(xa[j] * 4096.f);
    hb[j] = (_Float16)(xb[j] * 4096.f);
  }
  f16x4* Hr = (f16x4*)(H + (size_t)row * DD);
  Hr[lane] = ha; Hr[lane + 64] = hb;

  float s = a.x*a.x + a.y*a.y + a.z*a.z + a.w*a.w
          + b.x*b.x + b.y*b.y + b.z*b.z + b.w*b.w;
#pragma unroll
  for (int off = 32; off >= 1; off >>= 1) s += __shfl_down(s, off, 64);
  if (lane == 0) rowsq[row] = s;
}

// ---------------------------------------------------------------------------
// Kernel 1: HH screening GEMM + u32 screen-top selection.
// K-loop: verbatim R11 (no-LDS, global->reg frags, 2-deep ping-pong, proven).
// NEW: block covers a 512-row SUPERBLOCK (4 row-tiles of 128) x 128 cols;
// per-(lane,cf) cap-5 u32 lists PERSIST across the 4 tiles (64 rows/list);
// merges (d16/d32 snapshot + LDS wr-pair) run ONCE per block, not per tile.
// Selection risk: >=6 of a center's top-8 in one 64-row bin ~ 3e-5 total.
// partials: u32 [8192 centers][16 rsb][8].
// C layout (m89): col = lane&15, row = 4*(lane>>4) + reg.
// ---------------------------------------------------------------------------
__launch_bounds__(256, 3)
__global__ void gemm_top8(const _Float16* __restrict__ Hp,
                          const float* __restrict__ rowsq, u32* __restrict__ partials) {
  __shared__ u32 mg[128 * 8];                 // 4 KB wr-pair merge buffer
  const int tid  = (int)threadIdx.x;
  const int lane = tid & 63;
  const int w    = tid >> 6;                  // wave 0..3
  const int wr   = w >> 1, wc = w & 1;        // 2x2 wave grid
  // XCD swizzle (1024 % 8 == 0 -> bijective); cb fastest so consecutive
  // blocks on one XCD share the 512-row A panel (512 KB, L2-resident).
  const int q    = ((int)blockIdx.x & 7) * 128 + ((int)blockIdx.x >> 3);
  const int cb   = q & 63;                    // 64 col-blocks of 128
  const int rsb  = q >> 6;                    // 16 row-superblocks of 512
  const int jb   = cb * 128;
  const int lgrp = lane >> 4;                 // k-group / C row-group
  const int lidx = lane & 15;                 // A-row / B-col within frag

  const char* Bpb = (const char*)(Hp + (size_t)(jb + wc*64 + lidx) * DD) + lgrp*16;

#define LOADF(aa, bb, apb, ksv) do {                                            \
    _Pragma("unroll")                                                           \
    for (int t = 0; t < 4; ++t)                                                 \
      aa[t] = *(const f16x8*)((apb) + t*16384 + (ksv)*64);                      \
    _Pragma("unroll")                                                           \
    for (int u = 0; u < 4; ++u)                                                 \
      bb[u] = *(const f16x8*)(Bpb + u*16384 + (ksv)*64);                        \
  } while (0)

#define MFMAS(aa, bb) do {                                                      \
    _Pragma("unroll")                                                           \
    for (int rt = 0; rt < 4; ++rt)                                              \
      _Pragma("unroll")                                                         \
      for (int cf = 0; cf < 4; ++cf)                                            \
        acc[rt][cf] = __builtin_amdgcn_mfma_f32_16x16x32_f16(aa[rt], bb[cf],    \
                                                             acc[rt][cf], 0, 0, 0); \
  } while (0)

  u32 t5[4][5];                               // persistent per-cf screen lists
#pragma unroll
  for (int c = 0; c < 4; ++c)
#pragma unroll
    for (int s = 0; s < 5; ++s) t5[c][s] = 0xFFFFFFFFu;

  for (int tt = 0; tt < 4; ++tt) {            // 4 row-tiles of the superblock
    const int row0 = rsb * 512 + tt * 128;
    const char* Apb = (const char*)(Hp + (size_t)(row0 + wr*64 + lidx) * DD) + lgrp*16;

    f32x4 acc[4][4] = {};
    f16x8 a0[4], b0[4], a1[4], b1[4];
    LOADF(a0, b0, Apb, 0);
    LOADF(a1, b1, Apb, 1);
#pragma unroll
    for (int ks = 0; ks < 16; ks += 2) {      // K = 512 in chunks of 32
      MFMAS(a0, b0);
      if (ks + 2 < 16) LOADF(a0, b0, Apb, ks + 2);
      MFMAS(a1, b1);
      if (ks + 3 < 16) LOADF(a1, b1, Apb, ks + 3);
    }

    float4 sqr[4];
#pragma unroll
    for (int t = 0; t < 4; ++t)
      sqr[t] = *(const float4*)(rowsq + row0 + wr*64 + t*16 + lgrp*4);

#pragma unroll
    for (int cf = 0; cf < 4; ++cf) {
      const int jc = jb + wc*64 + cf*16 + lidx;   // this lane's center column
#pragma unroll
      for (int t = 0; t < 4; ++t) {
        const int rbase = row0 + wr*64 + t*16 + lgrp*4;
        const float sx[4] = {sqr[t].x, sqr[t].y, sqr[t].z, sqr[t].w};
#pragma unroll
        for (int qq = 0; qq < 4; ++qq) {
          const int r = rbase + qq;
          const float key = fmaf(acc[t][cf][qq], KSCALE, sx[qq]);
          u32 v = pk32(key, r);
          v = (r == jc) ? 0xFFFFFFFFu : v;    // branchless self-exclusion
          swins5(v, t5[cf]);
        }
      }
    }
  }

  // ---- merges once per block ----
#pragma unroll
  for (int cf = 0; cf < 4; ++cf) {
    const int jc = jb + wc*64 + cf*16 + lidx;
    u32 t8[8];
#pragma unroll
    for (int s = 0; s < 5; ++s) t8[s] = t5[cf][s];
#pragma unroll
    for (int s = 5; s < 8; ++s) t8[s] = 0xFFFFFFFFu;
    {                                          // d=16: partner lgrp pair (snapshot t5)
      u32 ov[5];
#pragma unroll
      for (int s = 0; s < 5; ++s) ov[s] = __shfl_xor(t5[cf][s], 16, 64);
#pragma unroll
      for (int s = 0; s < 5; ++s) swins8(ov[s], t8);
    }
    {                                          // d=32 (snapshot t8)
      u32 ov[8];
#pragma unroll
      for (int s = 0; s < 8; ++s) ov[s] = __shfl_xor(t8[s], 32, 64);
#pragma unroll
      for (int s = 0; s < 8; ++s) swins8(ov[s], t8);
    }
    // wr-pair merge via LDS (the two wr waves cover different 256-row halves)
    if (wr == 1 && lane < 16) {
#pragma unroll
      for (int s = 0; s < 8; ++s) mg[(wc*64 + cf*16 + lidx)*8 + s] = t8[s];
    }
    __syncthreads();
    if (wr == 0 && lane < 16) {
      const u32* om = &mg[(wc*64 + cf*16 + lidx)*8];
#pragma unroll
      for (int s = 0; s < 8; ++s) swins8(om[s], t8);
      u32* pw = partials + ((size_t)jc * 16 + rsb) * 8;
#pragma unroll
      for (int s = 0; s < 8; ++s) pw[s] = t8[s];
    }
    __syncthreads();                          // mg reused next cf
  }
#undef LOADF
#undef MFMAS
}

// ---------------------------------------------------------------------------
// Kernel 2: fold 128 u32 screen entries per center -> cand[T][8].
// One wave per center, 2 entries per lane, snapshot butterfly.
// ---------------------------------------------------------------------------
__global__ void merge_nn8(const u32* __restrict__ parts, u32* __restrict__ cand) {
  const int j    = (int)blockIdx.x * 4 + ((int)threadIdx.x >> 6);
  const int lane = (int)threadIdx.x & 63;
  u32 tv[8];
#pragma unroll
  for (int s = 0; s < 8; ++s) tv[s] = 0xFFFFFFFFu;
  swins8(parts[(size_t)j * 128 + lane], tv);
  swins8(parts[(size_t)j * 128 + 64 + lane], tv);
#pragma unroll
  for (int d = 1; d < 64; d <<= 1) {
    u32 ov[8];
#pragma unroll
    for (int s = 0; s < 8; ++s) ov[s] = __shfl_xor(tv[s], d, 64);
#pragma unroll
    for (int s = 0; s < 8; ++s) swins8(ov[s], tv);
  }
  if (lane == 0) {
#pragma unroll
    for (int s = 0; s < 8; ++s) cand[(size_t)j*8 + s] = tv[s];
  }
}

// ---------------------------------------------------------------------------
// Kernel 3: exact fp32 refine of the 8 candidates per center -> nn[T][5].
// (R8-proven; candidate idx now = low 13 bits of the u32 screen entry)
// ---------------------------------------------------------------------------
__global__ void refine_nn(const float* __restrict__ X, const float* __restrict__ rowsq,
                          const u32* __restrict__ cand, int* __restrict__ nn) {
  const int j    = (int)blockIdx.x * 4 + ((int)threadIdx.x >> 6);   // center
  const int lane = (int)threadIdx.x & 63;
  const float4* xj = (const float4*)(X + (size_t)j * DD);
  const float4 qa = xj[lane];
  const float4 qb = xj[lane + 64];
  u64 best[8];
#pragma unroll
  for (int s = 0; s < 8; ++s) best[s] = ~0ull;
#pragma unroll
  for (int c = 0; c < 8; ++c) {
    const int r = (int)(cand[(size_t)j*8 + c] & 8191u);
    const float4* xr_ = (const float4*)(X + (size_t)r * DD);
    const float4 a = xr_[lane];
    const float4 b = xr_[lane + 64];
    float d = a.x*qa.x + a.y*qa.y + a.z*qa.z + a.w*qa.w
            + b.x*qb.x + b.y*qb.y + b.z*qb.z + b.w*qb.w;
#pragma unroll
    for (int off = 32; off >= 1; off >>= 1) d += __shfl_xor(d, off, 64);
    const float key = fmaf(-2.f, d, rowsq[r]);
    ins8_64(packkey64(key, r), best);         // every lane: identical result
  }
  if (lane == 0) {
#pragma unroll
    for (int s = 0; s < KNN; ++s) nn[j*KNN + s] = (int)(u32)best[s];
  }
}

// ---------------------------------------------------------------------------
// Kernel 4: synthesis  out[i*4+p] = x_i + g * (x_nn - x_i)  (verbatim, proven)
// ---------------------------------------------------------------------------
__global__ void synth_kernel(const float* __restrict__ X, const int* __restrict__ nn,
                             const float* __restrict__ gaps, const int* __restrict__ choice,
                             float* __restrict__ out) {
  const float4* X4 = (const float4*)X;
  float4* O4 = (float4*)out;
  const int base = (int)blockIdx.x * 256 + (int)threadIdx.x;
#pragma unroll
  for (int it = 0; it < 8; ++it) {
    const int f    = base + it * (2048 * 256);
    const int orow = f >> 7;
    const int d4   = f & 127;
    const int i    = orow >> 2;
    const int ch   = choice[orow];
    const int nr   = nn[i * KNN + ch];
    const float g  = gaps[orow];
    const float4 xi = X4[(size_t)i  * 128 + d4];
    const float4 xn = X4[(size_t)nr * 128 + d4];
    float4 r;
    r.x = fmaf(g, xn.x - xi.x, xi.x);
    r.y = fmaf(g, xn.y - xi.y, xi.y);
    r.z = fmaf(g, xn.z - xi.z, xi.z);
    r.w = fmaf(g, xn.w - xi.w, xi.w);
    O4[(size_t)orow * 128 + d4] = r;
  }
}

// ---------------------------------------------------------------------------
// d_out (64 MB) scratch: H[0,8M) | partials u32[8M,12M) | cand[12M,12.25M)
// — synth fully rewrites d_out last. d_ws: rowsq[32KB) + nn[160KB).
// ---------------------------------------------------------------------------
extern "C" void kernel_launch(void* const* d_in, const int* in_sizes, int n_in,
                              void* d_out, int out_size, void* d_ws, size_t ws_size,
                              hipStream_t stream) {
  const float* X      = (const float*)d_in[0];
  const float* gaps   = (const float*)d_in[1];
  const int*   choice = (const int*)  d_in[2];
  float* out = (float*)d_out;

  _Float16* Hbuf  = (_Float16*)d_out;                       // [0, 8M)
  u32*      parts = (u32*)((char*)d_out + 8388608);         // [8M, 12M)
  u32*      cand  = (u32*)((char*)d_out + 12582912);        // [12M, 12.25M)

  float* rowsq = (float*)d_ws;                              // 32 KB
  int*   nn    = (int*)((char*)d_ws + TN * 4);              // 160 KB

  prep_sq     <<<2048, 256, 0, stream>>>(X, Hbuf, rowsq);
  gemm_top8   <<<1024, 256, 0, stream>>>(Hbuf, rowsq, parts);
  merge_nn8   <<<2048, 256, 0, stream>>>(parts, cand);
  refine_nn   <<<2048, 256, 0, stream>>>(X, rowsq, cand, nn);
  synth_kernel<<<2048, 256, 0, stream>>>(X, nn, gaps, choice, out);
}

// Round 14
// 306.709 us; speedup vs baseline: 2.7976x; 1.2283x over previous
//
#include <hip/hip_runtime.h>
#include <cstdint>
#include <cstddef>

#define TN   8192
#define DD   512
#define NPER 4
#define KNN  5

typedef _Float16 f16x8 __attribute__((ext_vector_type(8)));
typedef _Float16 f16x4 __attribute__((ext_vector_type(4)));
typedef float    f32x4 __attribute__((ext_vector_type(4)));
typedef unsigned int  u32;
typedef unsigned long long u64;

// key = sq_row - 2 * accHH / 4096^2  ->  fmaf(acc, -2^-23, sq_row)
#define KSCALE (-1.1920928955078125e-07f)

// ---------------------------------------------------------------------------
// u32 screen key: monotone f32 map, top 19 bits | 13-bit row idx.
// Quantization ~1.0 abs << NN rank gaps (~3); exact order restored by fp32
// refine; 8-slot screen vs 5 needed gives slack.  (validated R13)
// ---------------------------------------------------------------------------
__device__ __forceinline__ u32 pk32(float key, int idx) {
  u32 kb = __float_as_uint(key);
  kb ^= (((int)kb >> 31) | 0x80000000u);
  return (kb & 0xFFFFE000u) | (u32)idx;
}

// branchless sorted-insert sweeps (v_min_u32/v_max_u32 pairs — R11 lesson:
// guarded chains run at wave granularity, P(any lane fires)~1).
__device__ __forceinline__ void swins5(u32 v, u32 t[5]) {
#pragma unroll
  for (int s = 0; s < 5; ++s) {
    u32 lo = v < t[s] ? v : t[s];
    u32 hi = v < t[s] ? t[s] : v;
    t[s] = lo; v = hi;
  }
}
__device__ __forceinline__ void swins8(u32 v, u32 t[8]) {
#pragma unroll
  for (int s = 0; s < 8; ++s) {
    u32 lo = v < t[s] ? v : t[s];
    u32 hi = v < t[s] ? t[s] : v;
    t[s] = lo; v = hi;
  }
}

// u64 exact insert for the tiny refine kernel (proven R8-R13)
__device__ __forceinline__ u64 packkey64(float key, int idx) {
  u32 kb = __float_as_uint(key);
  kb ^= (((int)kb >> 31) | 0x80000000u);
  return ((u64)kb << 32) | (u32)idx;
}
__device__ __forceinline__ void ins8_64(u64 v, u64 tv[8]) {
  if (v < tv[7]) {
    tv[7] = v;
#pragma unroll
    for (int s = 7; s > 0; --s) {
      u64 lo = tv[s] < tv[s-1] ? tv[s] : tv[s-1];
      u64 hi = tv[s] < tv[s-1] ? tv[s-1] : tv[s];
      tv[s-1] = lo; tv[s] = hi;
    }
  }
}

// ---------------------------------------------------------------------------
// Kernel 0: hi fp16 of X*4096 AND exact rowsq. One wave per row.
// ---------------------------------------------------------------------------
__global__ void prep_sq(const float* __restrict__ X,
                        _Float16* __restrict__ H, float* __restrict__ rowsq) {
  const int row  = (int)blockIdx.x * 4 + ((int)threadIdx.x >> 6);
  const int lane = (int)threadIdx.x & 63;
  const float4* xr = (const float4*)(X + (size_t)row * DD);
  const float4 a = xr[lane];
  const float4 b = xr[lane + 64];
  float xa[4] = {a.x, a.y, a.z, a.w};
  float xb[4] = {b.x, b.y, b.z, b.w};
  f16x4 ha, hb;
#pragma unroll
  for (int j = 0; j < 4; ++j) {
    ha[j] = (_Float16)(xa[j] * 4096.f);
    hb[j] = (_Float16)(xb[j] * 4096.f);
  }
  f16x4* Hr = (f16x4*)(H + (size_t)row * DD);
  Hr[lane] = ha; Hr[lane + 64] = hb;

  float s = a.x*a.x + a.y*a.y + a.z*a.z + a.w*a.w
          + b.x*b.x + b.y*b.y + b.z*b.z + b.w*b.w;
#pragma unroll
  for (int off = 32; off >= 1; off >>= 1) s += __shfl_down(s, off, 64);
  if (lane == 0) rowsq[row] = s;
}

// ---------------------------------------------------------------------------
// Kernel 1: HH screening GEMM + u32 screen-top selection (structure = R13).
// 512-row superblock x 128 cols per block; per-(lane,cf) cap-5 u32 lists
// persist across the 4 row-tiles; merges once per block.
// launch_bounds(256,2): R13's (256,3) capped unified regs at ~170 while
// demand is ~174 (64 AGPR acc + 64 frag + 20 t5 + ~25 addr) -> spilled
// 239 MB of scratch writes/disp (the R2/R4 failure family, by 4 regs).
// 256-reg cap fits demand; 2 blocks/CU (8 waves) remains enough TLP
// (R11 ran at 2.65 waves/SIMD).
// C layout (m89): col = lane&15, row = 4*(lane>>4) + reg.
// partials: u32 [8192 centers][16 rsb][8].
// ---------------------------------------------------------------------------
__launch_bounds__(256, 2)
__global__ void gemm_top8(const _Float16* __restrict__ Hp,
                          const float* __restrict__ rowsq, u32* __restrict__ partials) {
  __shared__ u32 mg[128 * 8];                 // 4 KB wr-pair merge buffer
  const int tid  = (int)threadIdx.x;
  const int lane = tid & 63;
  const int w    = tid >> 6;                  // wave 0..3
  const int wr   = w >> 1, wc = w & 1;        // 2x2 wave grid
  // XCD swizzle (1024 % 8 == 0 -> bijective); cb fastest so consecutive
  // blocks on one XCD share the 512-row A panel (512 KB, L2-resident).
  const int q    = ((int)blockIdx.x & 7) * 128 + ((int)blockIdx.x >> 3);
  const int cb   = q & 63;                    // 64 col-blocks of 128
  const int rsb  = q >> 6;                    // 16 row-superblocks of 512
  const int jb   = cb * 128;
  const int lgrp = lane >> 4;                 // k-group / C row-group
  const int lidx = lane & 15;                 // A-row / B-col within frag

  const char* Bpb = (const char*)(Hp + (size_t)(jb + wc*64 + lidx) * DD) + lgrp*16;

#define LOADF(aa, bb, apb, ksv) do {                                            \
    _Pragma("unroll")                                                           \
    for (int t = 0; t < 4; ++t)                                                 \
      aa[t] = *(const f16x8*)((apb) + t*16384 + (ksv)*64);                      \
    _Pragma("unroll")                                                           \
    for (int u = 0; u < 4; ++u)                                                 \
      bb[u] = *(const f16x8*)(Bpb + u*16384 + (ksv)*64);                        \
  } while (0)

#define MFMAS(aa, bb) do {                                                      \
    _Pragma("unroll")                                                           \
    for (int rt = 0; rt < 4; ++rt)                                              \
      _Pragma("unroll")                                                         \
      for (int cf = 0; cf < 4; ++cf)                                            \
        acc[rt][cf] = __builtin_amdgcn_mfma_f32_16x16x32_f16(aa[rt], bb[cf],    \
                                                             acc[rt][cf], 0, 0, 0); \
  } while (0)

  u32 t5[4][5];                               // persistent per-cf screen lists
#pragma unroll
  for (int c = 0; c < 4; ++c)
#pragma unroll
    for (int s = 0; s < 5; ++s) t5[c][s] = 0xFFFFFFFFu;

  for (int tt = 0; tt < 4; ++tt) {            // 4 row-tiles of the superblock
    const int row0 = rsb * 512 + tt * 128;
    const char* Apb = (const char*)(Hp + (size_t)(row0 + wr*64 + lidx) * DD) + lgrp*16;

    f32x4 acc[4][4] = {};
    f16x8 a0[4], b0[4], a1[4], b1[4];
    LOADF(a0, b0, Apb, 0);
    LOADF(a1, b1, Apb, 1);
#pragma unroll
    for (int ks = 0; ks < 16; ks += 2) {      // K = 512 in chunks of 32
      MFMAS(a0, b0);
      if (ks + 2 < 16) LOADF(a0, b0, Apb, ks + 2);
      MFMAS(a1, b1);
      if (ks + 3 < 16) LOADF(a1, b1, Apb, ks + 3);
    }

    float4 sqr[4];
#pragma unroll
    for (int t = 0; t < 4; ++t)
      sqr[t] = *(const float4*)(rowsq + row0 + wr*64 + t*16 + lgrp*4);

#pragma unroll
    for (int cf = 0; cf < 4; ++cf) {
      const int jc = jb + wc*64 + cf*16 + lidx;   // this lane's center column
#pragma unroll
      for (int t = 0; t < 4; ++t) {
        const int rbase = row0 + wr*64 + t*16 + lgrp*4;
        const float sx[4] = {sqr[t].x, sqr[t].y, sqr[t].z, sqr[t].w};
#pragma unroll
        for (int qq = 0; qq < 4; ++qq) {
          const int r = rbase + qq;
          const float key = fmaf(acc[t][cf][qq], KSCALE, sx[qq]);
          u32 v = pk32(key, r);
          v = (r == jc) ? 0xFFFFFFFFu : v;    // branchless self-exclusion
          swins5(v, t5[cf]);
        }
      }
    }
  }

  // ---- merges once per block ----
#pragma unroll
  for (int cf = 0; cf < 4; ++cf) {
    const int jc = jb + wc*64 + cf*16 + lidx;
    u32 t8[8];
#pragma unroll
    for (int s = 0; s < 5; ++s) t8[s] = t5[cf][s];
#pragma unroll
    for (int s = 5; s < 8; ++s) t8[s] = 0xFFFFFFFFu;
    {                                          // d=16: partner lgrp pair (snapshot t5)
      u32 ov[5];
#pragma unroll
      for (int s = 0; s < 5; ++s) ov[s] = __shfl_xor(t5[cf][s], 16, 64);
#pragma unroll
      for (int s = 0; s < 5; ++s) swins8(ov[s], t8);
    }
    {                                          // d=32 (snapshot t8)
      u32 ov[8];
#pragma unroll
      for (int s = 0; s < 8; ++s) ov[s] = __shfl_xor(t8[s], 32, 64);
#pragma unroll
      for (int s = 0; s < 8; ++s) swins8(ov[s], t8);
    }
    // wr-pair merge via LDS (the two wr waves cover different 256-row halves)
    if (wr == 1 && lane < 16) {
#pragma unroll
      for (int s = 0; s < 8; ++s) mg[(wc*64 + cf*16 + lidx)*8 + s] = t8[s];
    }
    __syncthreads();
    if (wr == 0 && lane < 16) {
      const u32* om = &mg[(wc*64 + cf*16 + lidx)*8];
#pragma unroll
      for (int s = 0; s < 8; ++s) swins8(om[s], t8);
      u32* pw = partials + ((size_t)jc * 16 + rsb) * 8;
#pragma unroll
      for (int s = 0; s < 8; ++s) pw[s] = t8[s];
    }
    __syncthreads();                          // mg reused next cf
  }
#undef LOADF
#undef MFMAS
}

// ---------------------------------------------------------------------------
// Kernel 2: fold 128 u32 screen entries per center -> cand[T][8].
// One wave per center, 2 entries per lane, snapshot butterfly. (R13-proven)
// ---------------------------------------------------------------------------
__global__ void merge_nn8(const u32* __restrict__ parts, u32* __restrict__ cand) {
  const int j    = (int)blockIdx.x * 4 + ((int)threadIdx.x >> 6);
  const int lane = (int)threadIdx.x & 63;
  u32 tv[8];
#pragma unroll
  for (int s = 0; s < 8; ++s) tv[s] = 0xFFFFFFFFu;
  swins8(parts[(size_t)j * 128 + lane], tv);
  swins8(parts[(size_t)j * 128 + 64 + lane], tv);
#pragma unroll
  for (int d = 1; d < 64; d <<= 1) {
    u32 ov[8];
#pragma unroll
    for (int s = 0; s < 8; ++s) ov[s] = __shfl_xor(tv[s], d, 64);
#pragma unroll
    for (int s = 0; s < 8; ++s) swins8(ov[s], tv);
  }
  if (lane == 0) {
#pragma unroll
    for (int s = 0; s < 8; ++s) cand[(size_t)j*8 + s] = tv[s];
  }
}

// ---------------------------------------------------------------------------
// Kernel 3: exact fp32 refine of the 8 candidates per center -> nn[T][5].
// (R8-proven; candidate idx = low 13 bits of the u32 screen entry)
// ---------------------------------------------------------------------------
__global__ void refine_nn(const float* __restrict__ X, const float* __restrict__ rowsq,
                          const u32* __restrict__ cand, int* __restrict__ nn) {
  const int j    = (int)blockIdx.x * 4 + ((int)threadIdx.x >> 6);   // center
  const int lane = (int)threadIdx.x & 63;
  const float4* xj = (const float4*)(X + (size_t)j * DD);
  const float4 qa = xj[lane];
  const float4 qb = xj[lane + 64];
  u64 best[8];
#pragma unroll
  for (int s = 0; s < 8; ++s) best[s] = ~0ull;
#pragma unroll
  for (int c = 0; c < 8; ++c) {
    const int r = (int)(cand[(size_t)j*8 + c] & 8191u);
    const float4* xr_ = (const float4*)(X + (size_t)r * DD);
    const float4 a = xr_[lane];
    const float4 b = xr_[lane + 64];
    float d = a.x*qa.x + a.y*qa.y + a.z*qa.z + a.w*qa.w
            + b.x*qb.x + b.y*qb.y + b.z*qb.z + b.w*qb.w;
#pragma unroll
    for (int off = 32; off >= 1; off >>= 1) d += __shfl_xor(d, off, 64);
    const float key = fmaf(-2.f, d, rowsq[r]);
    ins8_64(packkey64(key, r), best);         // every lane: identical result
  }
  if (lane == 0) {
#pragma unroll
    for (int s = 0; s < KNN; ++s) nn[j*KNN + s] = (int)(u32)best[s];
  }
}

// ---------------------------------------------------------------------------
// Kernel 4: synthesis  out[i*4+p] = x_i + g * (x_nn - x_i)  (verbatim, proven)
// ---------------------------------------------------------------------------
__global__ void synth_kernel(const float* __restrict__ X, const int* __restrict__ nn,
                             const float* __restrict__ gaps, const int* __restrict__ choice,
                             float* __restrict__ out) {
  const float4* X4 = (const float4*)X;
  float4* O4 = (float4*)out;
  const int base = (int)blockIdx.x * 256 + (int)threadIdx.x;
#pragma unroll
  for (int it = 0; it < 8; ++it) {
    const int f    = base + it * (2048 * 256);
    const int orow = f >> 7;
    const int d4   = f & 127;
    const int i    = orow >> 2;
    const int ch   = choice[orow];
    const int nr   = nn[i * KNN + ch];
    const float g  = gaps[orow];
    const float4 xi = X4[(size_t)i  * 128 + d4];
    const float4 xn = X4[(size_t)nr * 128 + d4];
    float4 r;
    r.x = fmaf(g, xn.x - xi.x, xi.x);
    r.y = fmaf(g, xn.y - xi.y, xi.y);
    r.z = fmaf(g, xn.z - xi.z, xi.z);
    r.w = fmaf(g, xn.w - xi.w, xi.w);
    O4[(size_t)orow * 128 + d4] = r;
  }
}

// ---------------------------------------------------------------------------
// d_out (64 MB) scratch: H[0,8M) | partials u32[8M,12M) | cand[12M,12.25M)
// — synth fully rewrites d_out last. d_ws: rowsq[32KB) + nn[160KB).
// ---------------------------------------------------------------------------
extern "C" void kernel_launch(void* const* d_in, const int* in_sizes, int n_in,
                              void* d_out, int out_size, void* d_ws, size_t ws_size,
                              hipStream_t stream) {
  const float* X      = (const float*)d_in[0];
  const float* gaps   = (const float*)d_in[1];
  const int*   choice = (const int*)  d_in[2];
  float* out = (float*)d_out;

  _Float16* Hbuf  = (_Float16*)d_out;                       // [0, 8M)
  u32*      parts = (u32*)((char*)d_out + 8388608);         // [8M, 12M)
  u32*      cand  = (u32*)((char*)d_out + 12582912);        // [12M, 12.25M)

  float* rowsq = (float*)d_ws;                              // 32 KB
  int*   nn    = (int*)((char*)d_ws + TN * 4);              // 160 KB

  prep_sq     <<<2048, 256, 0, stream>>>(X, Hbuf, rowsq);
  gemm_top8   <<<1024, 256, 0, stream>>>(Hbuf, rowsq, parts);
  merge_nn8   <<<2048, 256, 0, stream>>>(parts, cand);
  refine_nn   <<<2048, 256, 0, stream>>>(X, rowsq, cand, nn);
  synth_kernel<<<2048, 256, 0, stream>>>(X, nn, gaps, choice, out);
}

// Round 15
// 240.128 us; speedup vs baseline: 3.5732x; 1.2773x over previous
//
#include <hip/hip_runtime.h>
#include <cstdint>
#include <cstddef>

#define TN   8192
#define DD   512
#define NPER 4
#define KNN  5

typedef _Float16 f16x8 __attribute__((ext_vector_type(8)));
typedef _Float16 f16x4 __attribute__((ext_vector_type(4)));
typedef float    f32x4 __attribute__((ext_vector_type(4)));
typedef unsigned int  u32;
typedef unsigned long long u64;

// key = sq_row - 2 * accHH / 4096^2  ->  fmaf(acc, -2^-23, sq_row)
#define KSCALE (-1.1920928955078125e-07f)

// ---------------------------------------------------------------------------
// u32 screen key: monotone f32 map, top 19 bits | 13-bit row idx. (R13/R14)
// ---------------------------------------------------------------------------
__device__ __forceinline__ u32 pk32(float key, int idx) {
  u32 kb = __float_as_uint(key);
  kb ^= (((int)kb >> 31) | 0x80000000u);
  return (kb & 0xFFFFE000u) | (u32)idx;
}

// branchless sorted-insert sweeps (v_min_u32/v_max_u32 pairs)
__device__ __forceinline__ void swins5(u32 v, u32 t[5]) {
#pragma unroll
  for (int s = 0; s < 5; ++s) {
    u32 lo = v < t[s] ? v : t[s];
    u32 hi = v < t[s] ? t[s] : v;
    t[s] = lo; v = hi;
  }
}
__device__ __forceinline__ void swins8(u32 v, u32 t[8]) {
#pragma unroll
  for (int s = 0; s < 8; ++s) {
    u32 lo = v < t[s] ? v : t[s];
    u32 hi = v < t[s] ? t[s] : v;
    t[s] = lo; v = hi;
  }
}

// u64 exact insert for the tiny refine kernel (proven R8-R14)
__device__ __forceinline__ u64 packkey64(float key, int idx) {
  u32 kb = __float_as_uint(key);
  kb ^= (((int)kb >> 31) | 0x80000000u);
  return ((u64)kb << 32) | (u32)idx;
}
__device__ __forceinline__ void ins8_64(u64 v, u64 tv[8]) {
  if (v < tv[7]) {
    tv[7] = v;
#pragma unroll
    for (int s = 7; s > 0; --s) {
      u64 lo = tv[s] < tv[s-1] ? tv[s] : tv[s-1];
      u64 hi = tv[s] < tv[s-1] ? tv[s-1] : tv[s];
      tv[s-1] = lo; tv[s] = hi;
    }
  }
}

// ---------------------------------------------------------------------------
// Kernel 0: hi fp16 of X*4096 AND exact rowsq. One wave per row.
// ---------------------------------------------------------------------------
__global__ void prep_sq(const float* __restrict__ X,
                        _Float16* __restrict__ H, float* __restrict__ rowsq) {
  const int row  = (int)blockIdx.x * 4 + ((int)threadIdx.x >> 6);
  const int lane = (int)threadIdx.x & 63;
  const float4* xr = (const float4*)(X + (size_t)row * DD);
  const float4 a = xr[lane];
  const float4 b = xr[lane + 64];
  float xa[4] = {a.x, a.y, a.z, a.w};
  float xb[4] = {b.x, b.y, b.z, b.w};
  f16x4 ha, hb;
#pragma unroll
  for (int j = 0; j < 4; ++j) {
    ha[j] = (_Float16)(xa[j] * 4096.f);
    hb[j] = (_Float16)(xb[j] * 4096.f);
  }
  f16x4* Hr = (f16x4*)(H + (size_t)row * DD);
  Hr[lane] = ha; Hr[lane + 64] = hb;

  float s = a.x*a.x + a.y*a.y + a.z*a.z + a.w*a.w
          + b.x*b.x + b.y*b.y + b.z*b.z + b.w*b.w;
#pragma unroll
  for (int off = 32; off >= 1; off >>= 1) s += __shfl_down(s, off, 64);
  if (lane == 0) rowsq[row] = s;
}

// ---------------------------------------------------------------------------
// Kernel 1: HH screening GEMM + u32 screen-top selection (structure = R14).
// 512-row superblock x 128 cols per block; per-(lane,cf) cap-5 u32 lists
// persist across the 4 row-tiles; merges once per block.
// launch_bounds(256,1): R14's (256,2) let the allocator pick a 128-arch
// budget and spill the cold t5 lists across each K-loop (138 MB scratch
// writes; 256 MB scratch working set blew L3 -> FETCH 334 MB for an 8 MB
// operand). Relaxing the cap to 512 removes the spill incentive; demand
// ~200-220 keeps usage <= 256 -> occupancy stays 2 waves/SIMD.
// C layout (m89): col = lane&15, row = 4*(lane>>4) + reg.
// partials: u32 [8192 centers][16 rsb][8].
// ---------------------------------------------------------------------------
__launch_bounds__(256, 1)
__global__ void gemm_top8(const _Float16* __restrict__ Hp,
                          const float* __restrict__ rowsq, u32* __restrict__ partials) {
  __shared__ u32 mg[128 * 8];                 // 4 KB wr-pair merge buffer
  const int tid  = (int)threadIdx.x;
  const int lane = tid & 63;
  const int w    = tid >> 6;                  // wave 0..3
  const int wr   = w >> 1, wc = w & 1;        // 2x2 wave grid
  // XCD swizzle (1024 % 8 == 0 -> bijective); cb fastest so consecutive
  // blocks on one XCD share the 512-row A panel (512 KB, L2-resident).
  const int q    = ((int)blockIdx.x & 7) * 128 + ((int)blockIdx.x >> 3);
  const int cb   = q & 63;                    // 64 col-blocks of 128
  const int rsb  = q >> 6;                    // 16 row-superblocks of 512
  const int jb   = cb * 128;
  const int lgrp = lane >> 4;                 // k-group / C row-group
  const int lidx = lane & 15;                 // A-row / B-col within frag

  const char* Bpb = (const char*)(Hp + (size_t)(jb + wc*64 + lidx) * DD) + lgrp*16;

#define LOADF(aa, bb, apb, ksv) do {                                            \
    _Pragma("unroll")                                                           \
    for (int t = 0; t < 4; ++t)                                                 \
      aa[t] = *(const f16x8*)((apb) + t*16384 + (ksv)*64);                      \
    _Pragma("unroll")                                                           \
    for (int u = 0; u < 4; ++u)                                                 \
      bb[u] = *(const f16x8*)(Bpb + u*16384 + (ksv)*64);                        \
  } while (0)

#define MFMAS(aa, bb) do {                                                      \
    _Pragma("unroll")                                                           \
    for (int rt = 0; rt < 4; ++rt)                                              \
      _Pragma("unroll")                                                         \
      for (int cf = 0; cf < 4; ++cf)                                            \
        acc[rt][cf] = __builtin_amdgcn_mfma_f32_16x16x32_f16(aa[rt], bb[cf],    \
                                                             acc[rt][cf], 0, 0, 0); \
  } while (0)

  u32 t5[4][5];                               // persistent per-cf screen lists
#pragma unroll
  for (int c = 0; c < 4; ++c)
#pragma unroll
    for (int s = 0; s < 5; ++s) t5[c][s] = 0xFFFFFFFFu;

  for (int tt = 0; tt < 4; ++tt) {            // 4 row-tiles of the superblock
    const int row0 = rsb * 512 + tt * 128;
    const char* Apb = (const char*)(Hp + (size_t)(row0 + wr*64 + lidx) * DD) + lgrp*16;

    f32x4 acc[4][4] = {};
    f16x8 a0[4], b0[4], a1[4], b1[4];
    LOADF(a0, b0, Apb, 0);
    LOADF(a1, b1, Apb, 1);
#pragma unroll
    for (int ks = 0; ks < 16; ks += 2) {      // K = 512 in chunks of 32
      MFMAS(a0, b0);
      if (ks + 2 < 16) LOADF(a0, b0, Apb, ks + 2);
      MFMAS(a1, b1);
      if (ks + 3 < 16) LOADF(a1, b1, Apb, ks + 3);
    }

    float4 sqr[4];
#pragma unroll
    for (int t = 0; t < 4; ++t)
      sqr[t] = *(const float4*)(rowsq + row0 + wr*64 + t*16 + lgrp*4);

#pragma unroll
    for (int cf = 0; cf < 4; ++cf) {
      const int jc = jb + wc*64 + cf*16 + lidx;   // this lane's center column
#pragma unroll
      for (int t = 0; t < 4; ++t) {
        const int rbase = row0 + wr*64 + t*16 + lgrp*4;
        const float sx[4] = {sqr[t].x, sqr[t].y, sqr[t].z, sqr[t].w};
#pragma unroll
        for (int qq = 0; qq < 4; ++qq) {
          const int r = rbase + qq;
          const float key = fmaf(acc[t][cf][qq], KSCALE, sx[qq]);
          u32 v = pk32(key, r);
          v = (r == jc) ? 0xFFFFFFFFu : v;    // branchless self-exclusion
          swins5(v, t5[cf]);
        }
      }
    }
  }

  // ---- merges once per block ----
#pragma unroll
  for (int cf = 0; cf < 4; ++cf) {
    const int jc = jb + wc*64 + cf*16 + lidx;
    u32 t8[8];
#pragma unroll
    for (int s = 0; s < 5; ++s) t8[s] = t5[cf][s];
#pragma unroll
    for (int s = 5; s < 8; ++s) t8[s] = 0xFFFFFFFFu;
    {                                          // d=16: partner lgrp pair (snapshot t5)
      u32 ov[5];
#pragma unroll
      for (int s = 0; s < 5; ++s) ov[s] = __shfl_xor(t5[cf][s], 16, 64);
#pragma unroll
      for (int s = 0; s < 5; ++s) swins8(ov[s], t8);
    }
    {                                          // d=32 (snapshot t8)
      u32 ov[8];
#pragma unroll
      for (int s = 0; s < 8; ++s) ov[s] = __shfl_xor(t8[s], 32, 64);
#pragma unroll
      for (int s = 0; s < 8; ++s) swins8(ov[s], t8);
    }
    // wr-pair merge via LDS (the two wr waves cover different 256-row halves)
    if (wr == 1 && lane < 16) {
#pragma unroll
      for (int s = 0; s < 8; ++s) mg[(wc*64 + cf*16 + lidx)*8 + s] = t8[s];
    }
    __syncthreads();
    if (wr == 0 && lane < 16) {
      const u32* om = &mg[(wc*64 + cf*16 + lidx)*8];
#pragma unroll
      for (int s = 0; s < 8; ++s) swins8(om[s], t8);
      u32* pw = partials + ((size_t)jc * 16 + rsb) * 8;
#pragma unroll
      for (int s = 0; s < 8; ++s) pw[s] = t8[s];
    }
    __syncthreads();                          // mg reused next cf
  }
#undef LOADF
#undef MFMAS
}

// ---------------------------------------------------------------------------
// Kernel 2: fold 128 u32 screen entries per center -> cand[T][8].
// One wave per center, 2 entries per lane, snapshot butterfly. (R13-proven)
// ---------------------------------------------------------------------------
__global__ void merge_nn8(const u32* __restrict__ parts, u32* __restrict__ cand) {
  const int j    = (int)blockIdx.x * 4 + ((int)threadIdx.x >> 6);
  const int lane = (int)threadIdx.x & 63;
  u32 tv[8];
#pragma unroll
  for (int s = 0; s < 8; ++s) tv[s] = 0xFFFFFFFFu;
  swins8(parts[(size_t)j * 128 + lane], tv);
  swins8(parts[(size_t)j * 128 + 64 + lane], tv);
#pragma unroll
  for (int d = 1; d < 64; d <<= 1) {
    u32 ov[8];
#pragma unroll
    for (int s = 0; s < 8; ++s) ov[s] = __shfl_xor(tv[s], d, 64);
#pragma unroll
    for (int s = 0; s < 8; ++s) swins8(ov[s], tv);
  }
  if (lane == 0) {
#pragma unroll
    for (int s = 0; s < 8; ++s) cand[(size_t)j*8 + s] = tv[s];
  }
}

// ---------------------------------------------------------------------------
// Kernel 3: exact fp32 refine of the 8 candidates per center -> nn[T][5].
// (R8-proven; candidate idx = low 13 bits of the u32 screen entry)
// ---------------------------------------------------------------------------
__global__ void refine_nn(const float* __restrict__ X, const float* __restrict__ rowsq,
                          const u32* __restrict__ cand, int* __restrict__ nn) {
  const int j    = (int)blockIdx.x * 4 + ((int)threadIdx.x >> 6);   // center
  const int lane = (int)threadIdx.x & 63;
  const float4* xj = (const float4*)(X + (size_t)j * DD);
  const float4 qa = xj[lane];
  const float4 qb = xj[lane + 64];
  u64 best[8];
#pragma unroll
  for (int s = 0; s < 8; ++s) best[s] = ~0ull;
#pragma unroll
  for (int c = 0; c < 8; ++c) {
    const int r = (int)(cand[(size_t)j*8 + c] & 8191u);
    const float4* xr_ = (const float4*)(X + (size_t)r * DD);
    const float4 a = xr_[lane];
    const float4 b = xr_[lane + 64];
    float d = a.x*qa.x + a.y*qa.y + a.z*qa.z + a.w*qa.w
            + b.x*qb.x + b.y*qb.y + b.z*qb.z + b.w*qb.w;
#pragma unroll
    for (int off = 32; off >= 1; off >>= 1) d += __shfl_xor(d, off, 64);
    const float key = fmaf(-2.f, d, rowsq[r]);
    ins8_64(packkey64(key, r), best);         // every lane: identical result
  }
  if (lane == 0) {
#pragma unroll
    for (int s = 0; s < KNN; ++s) nn[j*KNN + s] = (int)(u32)best[s];
  }
}

// ---------------------------------------------------------------------------
// Kernel 4: synthesis  out[i*4+p] = x_i + g * (x_nn - x_i)  (verbatim, proven)
// ---------------------------------------------------------------------------
__global__ void synth_kernel(const float* __restrict__ X, const int* __restrict__ nn,
                             const float* __restrict__ gaps, const int* __restrict__ choice,
                             float* __restrict__ out) {
  const float4* X4 = (const float4*)X;
  float4* O4 = (float4*)out;
  const int base = (int)blockIdx.x * 256 + (int)threadIdx.x;
#pragma unroll
  for (int it = 0; it < 8; ++it) {
    const int f    = base + it * (2048 * 256);
    const int orow = f >> 7;
    const int d4   = f & 127;
    const int i    = orow >> 2;
    const int ch   = choice[orow];
    const int nr   = nn[i * KNN + ch];
    const float g  = gaps[orow];
    const float4 xi = X4[(size_t)i  * 128 + d4];
    const float4 xn = X4[(size_t)nr * 128 + d4];
    float4 r;
    r.x = fmaf(g, xn.x - xi.x, xi.x);
    r.y = fmaf(g, xn.y - xi.y, xi.y);
    r.z = fmaf(g, xn.z - xi.z, xi.z);
    r.w = fmaf(g, xn.w - xi.w, xi.w);
    O4[(size_t)orow * 128 + d4] = r;
  }
}

// ---------------------------------------------------------------------------
// d_out (64 MB) scratch: H[0,8M) | partials u32[8M,12M) | cand[12M,12.25M)
// — synth fully rewrites d_out last. d_ws: rowsq[32KB) + nn[160KB).
// ---------------------------------------------------------------------------
extern "C" void kernel_launch(void* const* d_in, const int* in_sizes, int n_in,
                              void* d_out, int out_size, void* d_ws, size_t ws_size,
                              hipStream_t stream) {
  const float* X      = (const float*)d_in[0];
  const float* gaps   = (const float*)d_in[1];
  const int*   choice = (const int*)  d_in[2];
  float* out = (float*)d_out;

  _Float16* Hbuf  = (_Float16*)d_out;                       // [0, 8M)
  u32*      parts = (u32*)((char*)d_out + 8388608);         // [8M, 12M)
  u32*      cand  = (u32*)((char*)d_out + 12582912);        // [12M, 12.25M)

  float* rowsq = (float*)d_ws;                              // 32 KB
  int*   nn    = (int*)((char*)d_ws + TN * 4);              // 160 KB

  prep_sq     <<<2048, 256, 0, stream>>>(X, Hbuf, rowsq);
  gemm_top8   <<<1024, 256, 0, stream>>>(Hbuf, rowsq, parts);
  merge_nn8   <<<2048, 256, 0, stream>>>(parts, cand);
  refine_nn   <<<2048, 256, 0, stream>>>(X, rowsq, cand, nn);
  synth_kernel<<<2048, 256, 0, stream>>>(X, nn, gaps, choice, out);
}

// Round 16
// 238.560 us; speedup vs baseline: 3.5967x; 1.0066x over previous
//
#include <hip/hip_runtime.h>
#include <cstdint>
#include <cstddef>

#define TN   8192
#define DD   512
#define NPER 4
#define KNN  5

typedef _Float16 f16x8 __attribute__((ext_vector_type(8)));
typedef _Float16 f16x4 __attribute__((ext_vector_type(4)));
typedef float    f32x4 __attribute__((ext_vector_type(4)));
typedef unsigned int  u32;
typedef unsigned long long u64;

// key = sq_row - 2 * accHH / 4096^2  ->  fmaf(acc, -2^-23, sq_row)
#define KSCALE (-1.1920928955078125e-07f)

// ---------------------------------------------------------------------------
// u32 screen key: monotone f32 map, top 19 bits | 13-bit row idx. (R13-R15)
// ---------------------------------------------------------------------------
__device__ __forceinline__ u32 pk32(float key, int idx) {
  u32 kb = __float_as_uint(key);
  kb ^= (((int)kb >> 31) | 0x80000000u);
  return (kb & 0xFFFFE000u) | (u32)idx;
}

// branchless sorted-insert sweeps (v_min_u32/v_max_u32 pairs)
__device__ __forceinline__ void swins5(u32 v, u32 t[5]) {
#pragma unroll
  for (int s = 0; s < 5; ++s) {
    u32 lo = v < t[s] ? v : t[s];
    u32 hi = v < t[s] ? t[s] : v;
    t[s] = lo; v = hi;
  }
}
__device__ __forceinline__ void swins8(u32 v, u32 t[8]) {
#pragma unroll
  for (int s = 0; s < 8; ++s) {
    u32 lo = v < t[s] ? v : t[s];
    u32 hi = v < t[s] ? t[s] : v;
    t[s] = lo; v = hi;
  }
}

// u64 exact insert for the tiny refine kernel (proven R8-R15)
__device__ __forceinline__ u64 packkey64(float key, int idx) {
  u32 kb = __float_as_uint(key);
  kb ^= (((int)kb >> 31) | 0x80000000u);
  return ((u64)kb << 32) | (u32)idx;
}
__device__ __forceinline__ void ins8_64(u64 v, u64 tv[8]) {
  if (v < tv[7]) {
    tv[7] = v;
#pragma unroll
    for (int s = 7; s > 0; --s) {
      u64 lo = tv[s] < tv[s-1] ? tv[s] : tv[s-1];
      u64 hi = tv[s] < tv[s-1] ? tv[s-1] : tv[s];
      tv[s-1] = lo; tv[s] = hi;
    }
  }
}

// ---------------------------------------------------------------------------
// Kernel 0: hi fp16 of X*4096 AND exact rowsq. One wave per row.
// ---------------------------------------------------------------------------
__global__ void prep_sq(const float* __restrict__ X,
                        _Float16* __restrict__ H, float* __restrict__ rowsq) {
  const int row  = (int)blockIdx.x * 4 + ((int)threadIdx.x >> 6);
  const int lane = (int)threadIdx.x & 63;
  const float4* xr = (const float4*)(X + (size_t)row * DD);
  const float4 a = xr[lane];
  const float4 b = xr[lane + 64];
  float xa[4] = {a.x, a.y, a.z, a.w};
  float xb[4] = {b.x, b.y, b.z, b.w};
  f16x4 ha, hb;
#pragma unroll
  for (int j = 0; j < 4; ++j) {
    ha[j] = (_Float16)(xa[j] * 4096.f);
    hb[j] = (_Float16)(xb[j] * 4096.f);
  }
  f16x4* Hr = (f16x4*)(H + (size_t)row * DD);
  f16x4* Lr = (f16x4*)(H + (size_t)row * DD);   // unused alias
  Hr[lane] = ha; Hr[lane + 64] = hb;
  (void)Lr;

  float s = a.x*a.x + a.y*a.y + a.z*a.z + a.w*a.w
          + b.x*b.x + b.y*b.y + b.z*b.z + b.w*b.w;
#pragma unroll
  for (int off = 32; off >= 1; off >>= 1) s += __shfl_down(s, off, 64);
  if (lane == 0) rowsq[row] = s;
}

// ---------------------------------------------------------------------------
// Kernel 1: HH screening GEMM + u32 screen-top selection (structure = R15).
// NEW (R16): 4-deep fragment pipeline. R15 sits at 1 wave/SIMD (272 unified
// regs > 256), so all latency hiding is ILP; the 2-deep ping-pong's
// load->use distance (~130 cyc) < L2 latency (~300 cyc) -> MfmaUtil 13%.
// 4-deep makes the distance ~3 MFMAS rounds (~390+ cyc). Regs: 128 frag +
// 64 acc + 20 t5 + ~30 misc ~= 290 <= 512 cap, no spill, occupancy unchanged.
// Fully-unrolled ks loop keeps buffer indices static (rule #20).
// C layout (m89): col = lane&15, row = 4*(lane>>4) + reg.
// partials: u32 [8192 centers][16 rsb][8].
// ---------------------------------------------------------------------------
__launch_bounds__(256, 1)
__global__ void gemm_top8(const _Float16* __restrict__ Hp,
                          const float* __restrict__ rowsq, u32* __restrict__ partials) {
  __shared__ u32 mg[128 * 8];                 // 4 KB wr-pair merge buffer
  const int tid  = (int)threadIdx.x;
  const int lane = tid & 63;
  const int w    = tid >> 6;                  // wave 0..3
  const int wr   = w >> 1, wc = w & 1;        // 2x2 wave grid
  // XCD swizzle (1024 % 8 == 0 -> bijective); cb fastest so consecutive
  // blocks on one XCD share the 512-row A panel (512 KB, L2-resident).
  const int q    = ((int)blockIdx.x & 7) * 128 + ((int)blockIdx.x >> 3);
  const int cb   = q & 63;                    // 64 col-blocks of 128
  const int rsb  = q >> 6;                    // 16 row-superblocks of 512
  const int jb   = cb * 128;
  const int lgrp = lane >> 4;                 // k-group / C row-group
  const int lidx = lane & 15;                 // A-row / B-col within frag

  const char* Bpb = (const char*)(Hp + (size_t)(jb + wc*64 + lidx) * DD) + lgrp*16;

#define LOADF(dep, apb, ksv) do {                                               \
    _Pragma("unroll")                                                           \
    for (int t = 0; t < 4; ++t)                                                 \
      fa[dep][t] = *(const f16x8*)((apb) + t*16384 + (ksv)*64);                 \
    _Pragma("unroll")                                                           \
    for (int u = 0; u < 4; ++u)                                                 \
      fb[dep][u] = *(const f16x8*)(Bpb + u*16384 + (ksv)*64);                   \
  } while (0)

#define MFMAS(dep) do {                                                         \
    _Pragma("unroll")                                                           \
    for (int rt = 0; rt < 4; ++rt)                                              \
      _Pragma("unroll")                                                         \
      for (int cf = 0; cf < 4; ++cf)                                            \
        acc[rt][cf] = __builtin_amdgcn_mfma_f32_16x16x32_f16(fa[dep][rt],       \
                                        fb[dep][cf], acc[rt][cf], 0, 0, 0);     \
  } while (0)

  u32 t5[4][5];                               // persistent per-cf screen lists
#pragma unroll
  for (int c = 0; c < 4; ++c)
#pragma unroll
    for (int s = 0; s < 5; ++s) t5[c][s] = 0xFFFFFFFFu;

  for (int tt = 0; tt < 4; ++tt) {            // 4 row-tiles of the superblock
    const int row0 = rsb * 512 + tt * 128;
    const char* Apb = (const char*)(Hp + (size_t)(row0 + wr*64 + lidx) * DD) + lgrp*16;

    f32x4 acc[4][4] = {};
    f16x8 fa[4][4], fb[4][4];                 // 4-deep pipeline buffers
    LOADF(0, Apb, 0);
    LOADF(1, Apb, 1);
    LOADF(2, Apb, 2);
    LOADF(3, Apb, 3);
#pragma unroll
    for (int ks = 0; ks < 16; ++ks) {         // K = 512 in chunks of 32
      const int d = ks & 3;                   // static after unroll
      MFMAS(d);
      if (ks + 4 < 16) LOADF(d, Apb, ks + 4); // issue 4 chunks ahead
    }

    float4 sqr[4];
#pragma unroll
    for (int t = 0; t < 4; ++t)
      sqr[t] = *(const float4*)(rowsq + row0 + wr*64 + t*16 + lgrp*4);

#pragma unroll
    for (int cf = 0; cf < 4; ++cf) {
      const int jc = jb + wc*64 + cf*16 + lidx;   // this lane's center column
#pragma unroll
      for (int t = 0; t < 4; ++t) {
        const int rbase = row0 + wr*64 + t*16 + lgrp*4;
        const float sx[4] = {sqr[t].x, sqr[t].y, sqr[t].z, sqr[t].w};
#pragma unroll
        for (int qq = 0; qq < 4; ++qq) {
          const int r = rbase + qq;
          const float key = fmaf(acc[t][cf][qq], KSCALE, sx[qq]);
          u32 v = pk32(key, r);
          v = (r == jc) ? 0xFFFFFFFFu : v;    // branchless self-exclusion
          swins5(v, t5[cf]);
        }
      }
    }
  }

  // ---- merges once per block ----
#pragma unroll
  for (int cf = 0; cf < 4; ++cf) {
    const int jc = jb + wc*64 + cf*16 + lidx;
    u32 t8[8];
#pragma unroll
    for (int s = 0; s < 5; ++s) t8[s] = t5[cf][s];
#pragma unroll
    for (int s = 5; s < 8; ++s) t8[s] = 0xFFFFFFFFu;
    {                                          // d=16: partner lgrp pair (snapshot t5)
      u32 ov[5];
#pragma unroll
      for (int s = 0; s < 5; ++s) ov[s] = __shfl_xor(t5[cf][s], 16, 64);
#pragma unroll
      for (int s = 0; s < 5; ++s) swins8(ov[s], t8);
    }
    {                                          // d=32 (snapshot t8)
      u32 ov[8];
#pragma unroll
      for (int s = 0; s < 8; ++s) ov[s] = __shfl_xor(t8[s], 32, 64);
#pragma unroll
      for (int s = 0; s < 8; ++s) swins8(ov[s], t8);
    }
    // wr-pair merge via LDS (the two wr waves cover different 256-row halves)
    if (wr == 1 && lane < 16) {
#pragma unroll
      for (int s = 0; s < 8; ++s) mg[(wc*64 + cf*16 + lidx)*8 + s] = t8[s];
    }
    __syncthreads();
    if (wr == 0 && lane < 16) {
      const u32* om = &mg[(wc*64 + cf*16 + lidx)*8];
#pragma unroll
      for (int s = 0; s < 8; ++s) swins8(om[s], t8);
      u32* pw = partials + ((size_t)jc * 16 + rsb) * 8;
#pragma unroll
      for (int s = 0; s < 8; ++s) pw[s] = t8[s];
    }
    __syncthreads();                          // mg reused next cf
  }
#undef LOADF
#undef MFMAS
}

// ---------------------------------------------------------------------------
// Kernel 2: fold 128 u32 screen entries per center -> cand[T][8].
// One wave per center, 2 entries per lane, snapshot butterfly. (R13-proven)
// ---------------------------------------------------------------------------
__global__ void merge_nn8(const u32* __restrict__ parts, u32* __restrict__ cand) {
  const int j    = (int)blockIdx.x * 4 + ((int)threadIdx.x >> 6);
  const int lane = (int)threadIdx.x & 63;
  u32 tv[8];
#pragma unroll
  for (int s = 0; s < 8; ++s) tv[s] = 0xFFFFFFFFu;
  swins8(parts[(size_t)j * 128 + lane], tv);
  swins8(parts[(size_t)j * 128 + 64 + lane], tv);
#pragma unroll
  for (int d = 1; d < 64; d <<= 1) {
    u32 ov[8];
#pragma unroll
    for (int s = 0; s < 8; ++s) ov[s] = __shfl_xor(tv[s], d, 64);
#pragma unroll
    for (int s = 0; s < 8; ++s) swins8(ov[s], tv);
  }
  if (lane == 0) {
#pragma unroll
    for (int s = 0; s < 8; ++s) cand[(size_t)j*8 + s] = tv[s];
  }
}

// ---------------------------------------------------------------------------
// Kernel 3: exact fp32 refine of the 8 candidates per center -> nn[T][5].
// (R8-proven; candidate idx = low 13 bits of the u32 screen entry)
// ---------------------------------------------------------------------------
__global__ void refine_nn(const float* __restrict__ X, const float* __restrict__ rowsq,
                          const u32* __restrict__ cand, int* __restrict__ nn) {
  const int j    = (int)blockIdx.x * 4 + ((int)threadIdx.x >> 6);   // center
  const int lane = (int)threadIdx.x & 63;
  const float4* xj = (const float4*)(X + (size_t)j * DD);
  const float4 qa = xj[lane];
  const float4 qb = xj[lane + 64];
  u64 best[8];
#pragma unroll
  for (int s = 0; s < 8; ++s) best[s] = ~0ull;
#pragma unroll
  for (int c = 0; c < 8; ++c) {
    const int r = (int)(cand[(size_t)j*8 + c] & 8191u);
    const float4* xr_ = (const float4*)(X + (size_t)r * DD);
    const float4 a = xr_[lane];
    const float4 b = xr_[lane + 64];
    float d = a.x*qa.x + a.y*qa.y + a.z*qa.z + a.w*qa.w
            + b.x*qb.x + b.y*qb.y + b.z*qb.z + b.w*qb.w;
#pragma unroll
    for (int off = 32; off >= 1; off >>= 1) d += __shfl_xor(d, off, 64);
    const float key = fmaf(-2.f, d, rowsq[r]);
    ins8_64(packkey64(key, r), best);         // every lane: identical result
  }
  if (lane == 0) {
#pragma unroll
    for (int s = 0; s < KNN; ++s) nn[j*KNN + s] = (int)(u32)best[s];
  }
}

// ---------------------------------------------------------------------------
// Kernel 4: synthesis  out[i*4+p] = x_i + g * (x_nn - x_i)  (verbatim, proven)
// ---------------------------------------------------------------------------
__global__ void synth_kernel(const float* __restrict__ X, const int* __restrict__ nn,
                             const float* __restrict__ gaps, const int* __restrict__ choice,
                             float* __restrict__ out) {
  const float4* X4 = (const float4*)X;
  float4* O4 = (float4*)out;
  const int base = (int)blockIdx.x * 256 + (int)threadIdx.x;
#pragma unroll
  for (int it = 0; it < 8; ++it) {
    const int f    = base + it * (2048 * 256);
    const int orow = f >> 7;
    const int d4   = f & 127;
    const int i    = orow >> 2;
    const int ch   = choice[orow];
    const int nr   = nn[i * KNN + ch];
    const float g  = gaps[orow];
    const float4 xi = X4[(size_t)i  * 128 + d4];
    const float4 xn = X4[(size_t)nr * 128 + d4];
    float4 r;
    r.x = fmaf(g, xn.x - xi.x, xi.x);
    r.y = fmaf(g, xn.y - xi.y, xi.y);
    r.z = fmaf(g, xn.z - xi.z, xi.z);
    r.w = fmaf(g, xn.w - xi.w, xi.w);
    O4[(size_t)orow * 128 + d4] = r;
  }
}

// ---------------------------------------------------------------------------
// d_out (64 MB) scratch: H[0,8M) | partials u32[8M,12M) | cand[12M,12.25M)
// — synth fully rewrites d_out last. d_ws: rowsq[32KB) + nn[160KB).
// ---------------------------------------------------------------------------
extern "C" void kernel_launch(void* const* d_in, const int* in_sizes, int n_in,
                              void* d_out, int out_size, void* d_ws, size_t ws_size,
                              hipStream_t stream) {
  const float* X      = (const float*)d_in[0];
  const float* gaps   = (const float*)d_in[1];
  const int*   choice = (const int*)  d_in[2];
  float* out = (float*)d_out;

  _Float16* Hbuf  = (_Float16*)d_out;                       // [0, 8M)
  u32*      parts = (u32*)((char*)d_out + 8388608);         // [8M, 12M)
  u32*      cand  = (u32*)((char*)d_out + 12582912);        // [12M, 12.25M)

  float* rowsq = (float*)d_ws;                              // 32 KB
  int*   nn    = (int*)((char*)d_ws + TN * 4);              // 160 KB

  prep_sq     <<<2048, 256, 0, stream>>>(X, Hbuf, rowsq);
  gemm_top8   <<<1024, 256, 0, stream>>>(Hbuf, rowsq, parts);
  merge_nn8   <<<2048, 256, 0, stream>>>(parts, cand);
  refine_nn   <<<2048, 256, 0, stream>>>(X, rowsq, cand, nn);
  synth_kernel<<<2048, 256, 0, stream>>>(X, nn, gaps, choice, out);
}

// Round 17
// 160.262 us; speedup vs baseline: 5.3539x; 1.4886x over previous
//
#include <hip/hip_runtime.h>
#include <cstdint>
#include <cstddef>

#define TN   8192
#define DD   512
#define NPER 4
#define KNN  5

typedef _Float16 f16x8 __attribute__((ext_vector_type(8)));
typedef float    f32x4 __attribute__((ext_vector_type(4)));
typedef unsigned int  u32;
typedef unsigned long long u64;

// key = sq_row - 2 * accHH / 4096^2  ->  fmaf(acc, -2^-23, sq_row)
#define KSCALE (-1.1920928955078125e-07f)

// ---------------------------------------------------------------------------
// u32 screen key: monotone f32 map, top 19 bits | 13-bit row idx. (R13-R16)
// ---------------------------------------------------------------------------
__device__ __forceinline__ u32 pk32(float key, int idx) {
  u32 kb = __float_as_uint(key);
  kb ^= (((int)kb >> 31) | 0x80000000u);
  return (kb & 0xFFFFE000u) | (u32)idx;
}

// branchless sorted-insert sweeps (v_min_u32/v_max_u32 pairs)
__device__ __forceinline__ void swins5(u32 v, u32 t[5]) {
#pragma unroll
  for (int s = 0; s < 5; ++s) {
    u32 lo = v < t[s] ? v : t[s];
    u32 hi = v < t[s] ? t[s] : v;
    t[s] = lo; v = hi;
  }
}
__device__ __forceinline__ void swins8(u32 v, u32 t[8]) {
#pragma unroll
  for (int s = 0; s < 8; ++s) {
    u32 lo = v < t[s] ? v : t[s];
    u32 hi = v < t[s] ? t[s] : v;
    t[s] = lo; v = hi;
  }
}

// u64 exact insert for the tiny refine kernel (proven R8-R16)
__device__ __forceinline__ u64 packkey64(float key, int idx) {
  u32 kb = __float_as_uint(key);
  kb ^= (((int)kb >> 31) | 0x80000000u);
  return ((u64)kb << 32) | (u32)idx;
}
__device__ __forceinline__ void ins8_64(u64 v, u64 tv[8]) {
  if (v < tv[7]) {
    tv[7] = v;
#pragma unroll
    for (int s = 7; s > 0; --s) {
      u64 lo = tv[s] < tv[s-1] ? tv[s] : tv[s-1];
      u64 hi = tv[s] < tv[s-1] ? tv[s-1] : tv[s];
      tv[s-1] = lo; tv[s] = hi;
    }
  }
}

// ---------------------------------------------------------------------------
// Kernel 0a: rowsq[r] = sum_d X[r][d]^2 (exact fp32). One wave per row.
// ---------------------------------------------------------------------------
__global__ void rowsq_kernel(const float* __restrict__ X, float* __restrict__ rowsq) {
  const int row  = (int)blockIdx.x * 4 + ((int)threadIdx.x >> 6);
  const int lane = (int)threadIdx.x & 63;
  const float4* xr = (const float4*)(X + (size_t)row * DD);
  const float4 a = xr[lane];
  const float4 b = xr[lane + 64];
  float s = a.x*a.x + a.y*a.y + a.z*a.z + a.w*a.w
          + b.x*b.x + b.y*b.y + b.z*b.z + b.w*b.w;
#pragma unroll
  for (int off = 32; off >= 1; off >>= 1) s += __shfl_down(s, off, 64);
  if (lane == 0) rowsq[row] = s;
}

// ---------------------------------------------------------------------------
// Kernel 0b: write H = f16(X*4096) in MFMA-FRAGMENT-BLOCKED layout.
// Hb is [T/16 rowblks][16 kcs][1024 B]; within a sub-panel, byte lane*16
// holds the fragment for lane (lgrp=lane>>4, lidx=lane&15): 8 f16 of
// row rowblk*16+lidx, k = kc*32 + lgrp*8 .. +7.
// => every GEMM fragment load is ONE fully-contiguous 1 KB burst.
// (R16 diagnosis: scattered 16-line fragment loads occupy the TA ~64 cyc
// each; 2048 of them per block x 4 blocks/CU ~= 218 us = the whole gemm.)
// Grid 512 blocks (one per 16-row block), 256 thr; wave wv does kc=wv*4..+3.
// ---------------------------------------------------------------------------
__global__ void prep_blk(const float* __restrict__ X, _Float16* __restrict__ Hb) {
  const int rb16 = (int)blockIdx.x;            // 0..511
  const int tid  = (int)threadIdx.x;
  const int lane = tid & 63;
  const int wv   = tid >> 6;
  const int lgrp = lane >> 4;
  const int lidx = lane & 15;
  const float* src = X + (size_t)(rb16*16 + lidx) * DD + lgrp*8;
#pragma unroll
  for (int i = 0; i < 4; ++i) {
    const int kc = wv*4 + i;
    const float4 x0 = *(const float4*)(src + kc*32);
    const float4 x1 = *(const float4*)(src + kc*32 + 4);
    float xs[8] = {x0.x, x0.y, x0.z, x0.w, x1.x, x1.y, x1.z, x1.w};
    f16x8 h;
#pragma unroll
    for (int j = 0; j < 8; ++j) h[j] = (_Float16)(xs[j] * 4096.f);
    *(f16x8*)((char*)Hb + ((size_t)rb16*16 + kc)*1024 + lane*16) = h;
  }
}

// ---------------------------------------------------------------------------
// Kernel 1: HH screening GEMM + u32 screen-top selection (structure = R15/16,
// loads now from the blocked layout -> contiguous 1 KB per instruction).
// 512-row superblock x 128 cols; per-(lane,cf) cap-5 u32 lists persist
// across the 4 row-tiles; merges once per block. 3-deep fragment pipeline
// (96 frag regs; 4-deep's extra depth proved worthless in R16 — the wall
// was TA occupancy, now removed; 3-deep keeps unified regs ~<=255 for a
// shot at 2 waves/SIMD).
// C layout (m89): col = lane&15, row = 4*(lane>>4) + reg.
// partials: u32 [8192 centers][16 rsb][8].
// ---------------------------------------------------------------------------
__launch_bounds__(256, 1)
__global__ void gemm_top8(const _Float16* __restrict__ Hb,
                          const float* __restrict__ rowsq, u32* __restrict__ partials) {
  __shared__ u32 mg[128 * 8];                 // 4 KB wr-pair merge buffer
  const int tid  = (int)threadIdx.x;
  const int lane = tid & 63;
  const int w    = tid >> 6;                  // wave 0..3
  const int wr   = w >> 1, wc = w & 1;        // 2x2 wave grid
  // XCD swizzle (1024 % 8 == 0 -> bijective); cb fastest so consecutive
  // blocks on one XCD share the 512-row A panel (L2-resident).
  const int q    = ((int)blockIdx.x & 7) * 128 + ((int)blockIdx.x >> 3);
  const int cb   = q & 63;                    // 64 col-blocks of 128
  const int rsb  = q >> 6;                    // 16 row-superblocks of 512
  const int jb   = cb * 128;
  const int lgrp = lane >> 4;                 // k-group / C row-group
  const int lidx = lane & 15;                 // A-row / B-col within frag

  // blocked-layout base pointers: sub-panel (rowblk, ks) at
  // (rowblk*16 + ks)*1024 + lane*16;  rowblk = row/16.
  const char* Bpb = (const char*)Hb + (size_t)(cb*8 + wc*4)*16384 + lane*16;

#define LOADF(dep, apb, ksv) do {                                               \
    _Pragma("unroll")                                                           \
    for (int t = 0; t < 4; ++t)                                                 \
      fa[dep][t] = *(const f16x8*)((apb) + t*16384 + (ksv)*1024);               \
    _Pragma("unroll")                                                           \
    for (int u = 0; u < 4; ++u)                                                 \
      fb[dep][u] = *(const f16x8*)(Bpb + u*16384 + (ksv)*1024);                 \
  } while (0)

#define MFMAS(dep) do {                                                         \
    _Pragma("unroll")                                                           \
    for (int rt = 0; rt < 4; ++rt)                                              \
      _Pragma("unroll")                                                         \
      for (int cf = 0; cf < 4; ++cf)                                            \
        acc[rt][cf] = __builtin_amdgcn_mfma_f32_16x16x32_f16(fa[dep][rt],       \
                                        fb[dep][cf], acc[rt][cf], 0, 0, 0);     \
  } while (0)

  u32 t5[4][5];                               // persistent per-cf screen lists
#pragma unroll
  for (int c = 0; c < 4; ++c)
#pragma unroll
    for (int s = 0; s < 5; ++s) t5[c][s] = 0xFFFFFFFFu;

  for (int tt = 0; tt < 4; ++tt) {            // 4 row-tiles of the superblock
    const int row0 = rsb * 512 + tt * 128;
    const char* Apb = (const char*)Hb + (size_t)(rsb*32 + tt*8 + wr*4)*16384 + lane*16;

    f32x4 acc[4][4] = {};
    f16x8 fa[3][4], fb[3][4];                 // 3-deep pipeline buffers
    LOADF(0, Apb, 0);
    LOADF(1, Apb, 1);
    LOADF(2, Apb, 2);
#pragma unroll
    for (int ks = 0; ks < 16; ++ks) {         // K = 512 in chunks of 32
      const int d = ks % 3;                   // static after full unroll
      MFMAS(d);
      if (ks + 3 < 16) LOADF(d, Apb, ks + 3); // issue 3 chunks ahead
    }

    float4 sqr[4];
#pragma unroll
    for (int t = 0; t < 4; ++t)
      sqr[t] = *(const float4*)(rowsq + row0 + wr*64 + t*16 + lgrp*4);

#pragma unroll
    for (int cf = 0; cf < 4; ++cf) {
      const int jc = jb + wc*64 + cf*16 + lidx;   // this lane's center column
#pragma unroll
      for (int t = 0; t < 4; ++t) {
        const int rbase = row0 + wr*64 + t*16 + lgrp*4;
        const float sx[4] = {sqr[t].x, sqr[t].y, sqr[t].z, sqr[t].w};
#pragma unroll
        for (int qq = 0; qq < 4; ++qq) {
          const int r = rbase + qq;
          const float key = fmaf(acc[t][cf][qq], KSCALE, sx[qq]);
          u32 v = pk32(key, r);
          v = (r == jc) ? 0xFFFFFFFFu : v;    // branchless self-exclusion
          swins5(v, t5[cf]);
        }
      }
    }
  }

  // ---- merges once per block ----
#pragma unroll
  for (int cf = 0; cf < 4; ++cf) {
    const int jc = jb + wc*64 + cf*16 + lidx;
    u32 t8[8];
#pragma unroll
    for (int s = 0; s < 5; ++s) t8[s] = t5[cf][s];
#pragma unroll
    for (int s = 5; s < 8; ++s) t8[s] = 0xFFFFFFFFu;
    {                                          // d=16: partner lgrp pair (snapshot t5)
      u32 ov[5];
#pragma unroll
      for (int s = 0; s < 5; ++s) ov[s] = __shfl_xor(t5[cf][s], 16, 64);
#pragma unroll
      for (int s = 0; s < 5; ++s) swins8(ov[s], t8);
    }
    {                                          // d=32 (snapshot t8)
      u32 ov[8];
#pragma unroll
      for (int s = 0; s < 8; ++s) ov[s] = __shfl_xor(t8[s], 32, 64);
#pragma unroll
      for (int s = 0; s < 8; ++s) swins8(ov[s], t8);
    }
    // wr-pair merge via LDS (the two wr waves cover different 256-row halves)
    if (wr == 1 && lane < 16) {
#pragma unroll
      for (int s = 0; s < 8; ++s) mg[(wc*64 + cf*16 + lidx)*8 + s] = t8[s];
    }
    __syncthreads();
    if (wr == 0 && lane < 16) {
      const u32* om = &mg[(wc*64 + cf*16 + lidx)*8];
#pragma unroll
      for (int s = 0; s < 8; ++s) swins8(om[s], t8);
      u32* pw = partials + ((size_t)jc * 16 + rsb) * 8;
#pragma unroll
      for (int s = 0; s < 8; ++s) pw[s] = t8[s];
    }
    __syncthreads();                          // mg reused next cf
  }
#undef LOADF
#undef MFMAS
}

// ---------------------------------------------------------------------------
// Kernel 2: fold 128 u32 screen entries per center -> cand[T][8].
// One wave per center, 2 entries per lane, snapshot butterfly. (R13-proven)
// ---------------------------------------------------------------------------
__global__ void merge_nn8(const u32* __restrict__ parts, u32* __restrict__ cand) {
  const int j    = (int)blockIdx.x * 4 + ((int)threadIdx.x >> 6);
  const int lane = (int)threadIdx.x & 63;
  u32 tv[8];
#pragma unroll
  for (int s = 0; s < 8; ++s) tv[s] = 0xFFFFFFFFu;
  swins8(parts[(size_t)j * 128 + lane], tv);
  swins8(parts[(size_t)j * 128 + 64 + lane], tv);
#pragma unroll
  for (int d = 1; d < 64; d <<= 1) {
    u32 ov[8];
#pragma unroll
    for (int s = 0; s < 8; ++s) ov[s] = __shfl_xor(tv[s], d, 64);
#pragma unroll
    for (int s = 0; s < 8; ++s) swins8(ov[s], tv);
  }
  if (lane == 0) {
#pragma unroll
    for (int s = 0; s < 8; ++s) cand[(size_t)j*8 + s] = tv[s];
  }
}

// ---------------------------------------------------------------------------
// Kernel 3: exact fp32 refine of the 8 candidates per center -> nn[T][5].
// (R8-proven; candidate idx = low 13 bits of the u32 screen entry)
// ---------------------------------------------------------------------------
__global__ void refine_nn(const float* __restrict__ X, const float* __restrict__ rowsq,
                          const u32* __restrict__ cand, int* __restrict__ nn) {
  const int j    = (int)blockIdx.x * 4 + ((int)threadIdx.x >> 6);   // center
  const int lane = (int)threadIdx.x & 63;
  const float4* xj = (const float4*)(X + (size_t)j * DD);
  const float4 qa = xj[lane];
  const float4 qb = xj[lane + 64];
  u64 best[8];
#pragma unroll
  for (int s = 0; s < 8; ++s) best[s] = ~0ull;
#pragma unroll
  for (int c = 0; c < 8; ++c) {
    const int r = (int)(cand[(size_t)j*8 + c] & 8191u);
    const float4* xr_ = (const float4*)(X + (size_t)r * DD);
    const float4 a = xr_[lane];
    const float4 b = xr_[lane + 64];
    float d = a.x*qa.x + a.y*qa.y + a.z*qa.z + a.w*qa.w
            + b.x*qb.x + b.y*qb.y + b.z*qb.z + b.w*qb.w;
#pragma unroll
    for (int off = 32; off >= 1; off >>= 1) d += __shfl_xor(d, off, 64);
    const float key = fmaf(-2.f, d, rowsq[r]);
    ins8_64(packkey64(key, r), best);         // every lane: identical result
  }
  if (lane == 0) {
#pragma unroll
    for (int s = 0; s < KNN; ++s) nn[j*KNN + s] = (int)(u32)best[s];
  }
}

// ---------------------------------------------------------------------------
// Kernel 4: synthesis  out[i*4+p] = x_i + g * (x_nn - x_i)  (verbatim, proven)
// ---------------------------------------------------------------------------
__global__ void synth_kernel(const float* __restrict__ X, const int* __restrict__ nn,
                             const float* __restrict__ gaps, const int* __restrict__ choice,
                             float* __restrict__ out) {
  const float4* X4 = (const float4*)X;
  float4* O4 = (float4*)out;
  const int base = (int)blockIdx.x * 256 + (int)threadIdx.x;
#pragma unroll
  for (int it = 0; it < 8; ++it) {
    const int f    = base + it * (2048 * 256);
    const int orow = f >> 7;
    const int d4   = f & 127;
    const int i    = orow >> 2;
    const int ch   = choice[orow];
    const int nr   = nn[i * KNN + ch];
    const float g  = gaps[orow];
    const float4 xi = X4[(size_t)i  * 128 + d4];
    const float4 xn = X4[(size_t)nr * 128 + d4];
    float4 r;
    r.x = fmaf(g, xn.x - xi.x, xi.x);
    r.y = fmaf(g, xn.y - xi.y, xi.y);
    r.z = fmaf(g, xn.z - xi.z, xi.z);
    r.w = fmaf(g, xn.w - xi.w, xi.w);
    O4[(size_t)orow * 128 + d4] = r;
  }
}

// ---------------------------------------------------------------------------
// d_out (64 MB) scratch: Hb[0,8M) | partials u32[8M,12M) | cand[12M,12.25M)
// — synth fully rewrites d_out last. d_ws: rowsq[32KB) + nn[160KB).
// ---------------------------------------------------------------------------
extern "C" void kernel_launch(void* const* d_in, const int* in_sizes, int n_in,
                              void* d_out, int out_size, void* d_ws, size_t ws_size,
                              hipStream_t stream) {
  const float* X      = (const float*)d_in[0];
  const float* gaps   = (const float*)d_in[1];
  const int*   choice = (const int*)  d_in[2];
  float* out = (float*)d_out;

  _Float16* Hb    = (_Float16*)d_out;                       // [0, 8M) blocked
  u32*      parts = (u32*)((char*)d_out + 8388608);         // [8M, 12M)
  u32*      cand  = (u32*)((char*)d_out + 12582912);        // [12M, 12.25M)

  float* rowsq = (float*)d_ws;                              // 32 KB
  int*   nn    = (int*)((char*)d_ws + TN * 4);              // 160 KB

  rowsq_kernel<<<2048, 256, 0, stream>>>(X, rowsq);
  prep_blk    <<<512,  256, 0, stream>>>(X, Hb);
  gemm_top8   <<<1024, 256, 0, stream>>>(Hb, rowsq, parts);
  merge_nn8   <<<2048, 256, 0, stream>>>(parts, cand);
  refine_nn   <<<2048, 256, 0, stream>>>(X, rowsq, cand, nn);
  synth_kernel<<<2048, 256, 0, stream>>>(X, nn, gaps, choice, out);
}